// Round 9
// baseline (326.563 us; speedup 1.0000x reference)
//
#include <hip/hip_runtime.h>
#include <hip/hip_bf16.h>
#include <cstdint>
#include <cstddef>

typedef unsigned short u16;
typedef __bf16 bf16x8 __attribute__((ext_vector_type(8)));
typedef __bf16 bf16x4 __attribute__((ext_vector_type(4)));
typedef short   s16x4 __attribute__((ext_vector_type(4)));
typedef float    f32x4 __attribute__((ext_vector_type(4)));
typedef unsigned short u16x2 __attribute__((ext_vector_type(2)));
typedef unsigned short u16x4 __attribute__((ext_vector_type(4)));
typedef unsigned short u16x8 __attribute__((ext_vector_type(8)));

#define DEVI static __device__ __forceinline__

DEVI float b2f(u16 u){ union{unsigned i; float v;} x; x.i=((unsigned)u)<<16; return x.v; }
DEVI u16 f2b(float f){ union{float v; unsigned i;} x; x.v=f; unsigned r=x.i+0x7FFFu+((x.i>>16)&1u); return (u16)(r>>16); }
DEVI f32x4 mfma16(bf16x8 a, bf16x8 b, f32x4 c){ return __builtin_amdgcn_mfma_f32_16x16x32_bf16(a,b,c,0,0,0); }
DEVI f32x4 mfma16k16(bf16x4 a, bf16x4 b, f32x4 c){
#if __has_builtin(__builtin_amdgcn_mfma_f32_16x16x16_bf16)
  return __builtin_amdgcn_mfma_f32_16x16x16_bf16(a,b,c,0,0,0);
#elif __has_builtin(__builtin_amdgcn_mfma_f32_16x16x16bf16_1k)
  return __builtin_amdgcn_mfma_f32_16x16x16bf16_1k((s16x4)a,(s16x4)b,c,0,0,0);
#else
  asm volatile("v_mfma_f32_16x16x16_bf16 %0, %1, %2, %0" : "+v"(c) : "v"(a), "v"(b));
  return c;
#endif
}
DEVI float fexp2(float x){ return __builtin_amdgcn_exp2f(x); }
DEVI void gload16(const void* g, void* l){
  __builtin_amdgcn_global_load_lds((const __attribute__((address_space(1))) void*)g,
                                   (__attribute__((address_space(3))) void*)l, 16, 0, 0);
}
DEVI float silu_f(float x){ return x/(1.f+__expf(-x)); }

// ---------------- workspace layout (bytes) ----------------
static constexpr size_t OFF_WC   = 0;
static constexpr size_t OFF_WQKV = OFF_WC   + (size_t)1024*1024*2;
static constexpr size_t OFF_WPROJ= OFF_WQKV + (size_t)3072*1024*2;
static constexpr size_t OFF_WEXP = OFF_WPROJ+ (size_t)1024*1024*2;
static constexpr size_t OFF_WW12 = OFF_WEXP + (size_t)1024*1024*2;
static constexpr size_t OFF_WW3  = OFF_WW12 + (size_t)5632*1024*2;
static constexpr size_t OFF_ADA  = OFF_WW3  + (size_t)1024*2752*2;
static constexpr size_t OFF_X2   = OFF_ADA  + (size_t)4*6144*4;
static constexpr size_t OFF_P1   = OFF_X2   + (size_t)4096*1024*4;
static constexpr size_t OFF_H1   = OFF_P1;
static constexpr size_t OFF_HC   = OFF_H1   + (size_t)4096*1024*2;
static constexpr size_t OFF_QKVO = OFF_HC   + (size_t)4096*1024*2;
static constexpr size_t OFF_X12  = OFF_P1;                       // reuse: h1/hc/qkvO dead
static constexpr size_t OFF_P2   = OFF_P1   + (size_t)4096*5632*2;
static constexpr size_t OFF_Q    = OFF_P2;
static constexpr size_t OFF_K    = OFF_Q    + (size_t)64*1024*64*2;
static constexpr size_t OFF_VT   = OFF_K    + (size_t)64*1024*64*2;
static constexpr size_t OFF_O    = OFF_VT   + (size_t)64*1024*64*2;
static constexpr size_t OFF_PR   = OFF_O    + (size_t)4096*1024*2;
static constexpr size_t OFF_H2   = OFF_PR   + (size_t)4096*1024*2;
static constexpr size_t OFF_HID  = OFF_P2;                       // reuse: q/k/vt dead

// ---------------- fp32 -> bf16 weight conversion with zero padding ----------------
__global__ __launch_bounds__(256) void convert_pad(const float* __restrict__ src, u16* __restrict__ dst,
                                                   int R, int C, int Cpad)
{
  int r = blockIdx.y;
  int c0 = (blockIdx.x*256 + threadIdx.x)*4;
  if (c0 >= Cpad) return;
  u16x4 o;
#pragma unroll
  for (int j=0;j<4;j++){
    int cc = c0+j;
    float f = (r < R && cc < C) ? src[(size_t)r*C + cc] : 0.f;
    o[j] = f2b(f);
  }
  *(u16x4*)&dst[(size_t)r*Cpad + c0] = o;
}

// ---------------- adaLN: ada = silu(c) @ ada_w.T + ada_b  -> [4][6144] fp32 ----------------
__global__ __launch_bounds__(256) void ada_kernel(const float* __restrict__ c,
    const float* __restrict__ aw, const float* __restrict__ ab, float* __restrict__ ada)
{
  __shared__ float s[4][1024];
  int t = threadIdx.x;
#pragma unroll
  for (int i=0;i<16;i++){
    int idx = i*256 + t;
    float cv = c[idx];
    s[idx>>10][idx&1023] = cv/(1.f+__expf(-cv));
  }
  __syncthreads();
  int wid = t>>6, lane = t&63;
  int j = blockIdx.x*4 + wid;
  const f32x4* wp = (const f32x4*)(aw + (size_t)j*1024);
  float a0=0,a1=0,a2=0,a3=0;
#pragma unroll
  for (int i=0;i<4;i++){
    f32x4 wv = wp[i*64 + lane];
    int k0 = (i*64+lane)*4;
#pragma unroll
    for (int e=0;e<4;e++){
      float w = wv[e];
      a0 += w*s[0][k0+e]; a1 += w*s[1][k0+e]; a2 += w*s[2][k0+e]; a3 += w*s[3][k0+e];
    }
  }
#pragma unroll
  for (int mask=1; mask<64; mask<<=1){
    a0 += __shfl_xor(a0, mask); a1 += __shfl_xor(a1, mask);
    a2 += __shfl_xor(a2, mask); a3 += __shfl_xor(a3, mask);
  }
  if (lane==0){
    float bv = ab[j];
    ada[0*6144 + j] = a0 + bv;
    ada[1*6144 + j] = a1 + bv;
    ada[2*6144 + j] = a2 + bv;
    ada[3*6144 + j] = a3 + bv;
  }
}

// ---------------- fused RMSNorm + modulate -> bf16 ----------------
__global__ __launch_bounds__(256) void rms_mod(const float* __restrict__ x,
    const float* __restrict__ w, const float* __restrict__ ada, int chunkSh,
    u16* __restrict__ out)
{
  int row = blockIdx.x;
  int b = row>>10;
  int t = threadIdx.x;
  int wid = t>>6, lane = t&63;
  f32x4 v = *(const f32x4*)(x + (size_t)row*1024 + t*4);
  float ss = v[0]*v[0]+v[1]*v[1]+v[2]*v[2]+v[3]*v[3];
#pragma unroll
  for (int mask=1; mask<64; mask<<=1) ss += __shfl_xor(ss, mask);
  __shared__ float red[4];
  if (lane==0) red[wid]=ss;
  __syncthreads();
  float rinv = rsqrtf((red[0]+red[1]+red[2]+red[3])*(1.f/1024.f) + 1e-6f);
  int cc = t*4;
  const float* shp = ada + (size_t)b*6144 + (size_t)chunkSh*1024 + cc;
  u16x4 o;
#pragma unroll
  for (int jj=0;jj<4;jj++){
    float val = v[jj]*rinv*w[cc+jj];
    val = val*(1.f+shp[jj+1024]) + shp[jj];
    o[jj] = f2b(val);
  }
  *(u16x4*)&out[(size_t)row*1024 + cc] = o;
}

// ---------------- bf16 GEMM 128x128 (BK=32), ring-5 LDS (80KB, 2 blocks/CU), depth-4 pipeline ----------------
// Grid must be (nbn, 32). XCD-aware remap: each XCD owns 4 contiguous A-stripes (bijective, nwg%8==0).
// EPI 0: bf16 out ld=N. EPI 1: outf = xres + gate*(acc+bias), ld=1024.
template<int EPI>
__global__ __launch_bounds__(256) void gemm_dr(
    const u16* __restrict__ A, const u16* __restrict__ Bw, const float* __restrict__ bias,
    int N, int K, int nbias, u16* __restrict__ outb,
    const float* __restrict__ xres, const float* __restrict__ ada, int adaChunk,
    float* __restrict__ outf)
{
  constexpr int RU = 8192;                 // (128 A-rows + 128 B-rows) * 32 u16
  __shared__ __align__(16) u16 lds[5*RU];  // 80 KB -> 2 blocks/CU
  int t = threadIdx.x;
  int lane = t&63, w = t>>6;
  int wr = (w>>1)*64, wc = (w&1)*64;
  int lr = lane&15, lg = lane>>4;
  // XCD remap: grid (nbn, 32); id%8 = XCD; each XCD gets 4 bm-stripes x nbn bn.
  int nbn = gridDim.x;
  int id = blockIdx.y*nbn + blockIdx.x;
  int xcd = id&7, loc = id>>3;
  int q = 0;
  while (loc >= nbn){ loc -= nbn; ++q; }   // q = loc/nbn (<=3 iters), loc = loc%nbn
  int bm = xcd*4 + q;
  int bn = loc;
  int srow = t>>2;
  int schunk = ((t&3) ^ (srow&3))*8;       // pre-swizzled global source chunk
  const u16* pA = A  + (size_t)(bm*128 + srow)*K + schunk;
  const u16* pB = Bw + (size_t)(bn*128 + srow)*K + schunk;
  int rp = (lg ^ (lr&3))*8;                // swizzled read position
  int aoff = (wr + lr)*32 + rp;
  int boff = 4096 + (wc + lr)*32 + rp;
  f32x4 acc[4][4] = {};
  int NT = K>>5;

  auto stage = [&](int kt, int slot){
    u16* dst = &lds[slot*RU];
    const u16* sa = pA + (size_t)kt*32;
    const u16* sb = pB + (size_t)kt*32;
    gload16(sa,                dst + t*8);
    gload16(sa + (size_t)64*K, dst + 2048 + t*8);
    gload16(sb,                dst + 4096 + t*8);
    gload16(sb + (size_t)64*K, dst + 6144 + t*8);
  };
  auto compute = [&](int slot){
    const u16* lb = &lds[slot*RU];
    bf16x8 af[4], bfr[4];
#pragma unroll
    for (int m=0;m<4;m++) af[m]  = *(const bf16x8*)&lb[aoff + m*512];
#pragma unroll
    for (int n=0;n<4;n++) bfr[n] = *(const bf16x8*)&lb[boff + n*512];
    __builtin_amdgcn_s_setprio(1);
#pragma unroll
    for (int m=0;m<4;m++)
#pragma unroll
      for (int n=0;n<4;n++)
        acc[m][n] = mfma16(af[m], bfr[n], acc[m][n]);
    __builtin_amdgcn_s_setprio(0);
  };

  // prologue: stage tiles 0..3 into slots 0..3 (16 loads in flight)
#pragma unroll
  for (int i=0;i<4;i++) stage(i, i);
  asm volatile("s_waitcnt vmcnt(12)" ::: "memory");   // tile 0 ready
  __builtin_amdgcn_s_barrier();
  __builtin_amdgcn_sched_barrier(0);

  int cur = 0, stg = 4;
  for (int kt=0; kt<NT-4; ++kt){
    stage(kt+4, stg);
    compute(cur);
    asm volatile("s_waitcnt vmcnt(12)" ::: "memory"); // next tile ready, 12 stay in flight
    __builtin_amdgcn_s_barrier();
    __builtin_amdgcn_sched_barrier(0);
    cur = (cur==4)?0:cur+1;
    stg = (stg==4)?0:stg+1;
  }
  // tail: 4 tiles, drain 12 -> 8 -> 4 -> 0
  compute(cur); cur=(cur==4)?0:cur+1;
  asm volatile("s_waitcnt vmcnt(8)" ::: "memory");
  __builtin_amdgcn_s_barrier(); __builtin_amdgcn_sched_barrier(0);
  compute(cur); cur=(cur==4)?0:cur+1;
  asm volatile("s_waitcnt vmcnt(4)" ::: "memory");
  __builtin_amdgcn_s_barrier(); __builtin_amdgcn_sched_barrier(0);
  compute(cur); cur=(cur==4)?0:cur+1;
  asm volatile("s_waitcnt vmcnt(0)" ::: "memory");
  __builtin_amdgcn_s_barrier(); __builtin_amdgcn_sched_barrier(0);
  compute(cur);

#pragma unroll
  for (int n=0;n<4;n++){
    int col = bn*128 + wc + n*16 + lr;
    float bv = (col < nbias) ? bias[col] : 0.f;
#pragma unroll
    for (int m=0;m<4;m++){
      int row0 = bm*128 + wr + m*16 + lg*4;
#pragma unroll
      for (int r=0;r<4;r++){
        int row = row0 + r;
        float v = acc[m][n][r] + bv;
        if constexpr (EPI==0){
          outb[(size_t)row*N + col] = f2b(v);
        } else {
          int bb = row>>10;
          float g = ada[(size_t)bb*6144 + (size_t)adaChunk*1024 + col];
          outf[(size_t)row*1024 + col] = xres[(size_t)row*1024 + col] + g*v;
        }
      }
    }
  }
}

// ---------------- qkv repack: rms-norm q,k per head, fragment-major K/V for attention ----------------
__global__ __launch_bounds__(256) void repack_qkv(const u16* __restrict__ qkvO,
    const float* __restrict__ qnw, const float* __restrict__ knw,
    u16* __restrict__ qO, u16* __restrict__ kO, u16* __restrict__ vO)
{
  __shared__ u16 ldsv[64][64];
  int bh = blockIdx.y, b = bh>>4, h = bh&15;
  int n0 = blockIdx.x*64;
  int t = threadIdx.x;
  int nr = t>>2, qd = (t&3)*16;
  const u16* rowp = qkvO + (size_t)(b*1024 + n0 + nr)*3072;
  // Q: rms-norm * qn_w * (1/8)*log2e
  {
    u16x8 a0 = *(const u16x8*)(rowp + h*64 + qd);
    u16x8 a1 = *(const u16x8*)(rowp + h*64 + qd + 8);
    float f[16]; float ss=0;
#pragma unroll
    for (int jj=0;jj<8;jj++){ f[jj]=b2f(a0[jj]); f[8+jj]=b2f(a1[jj]); }
#pragma unroll
    for (int jj=0;jj<16;jj++) ss += f[jj]*f[jj];
    ss += __shfl_xor(ss,1); ss += __shfl_xor(ss,2);
    float rinv = rsqrtf(ss*(1.f/64.f)+1e-6f)*0.125f*1.44269504089f;
    u16x8 o0,o1;
#pragma unroll
    for (int jj=0;jj<8;jj++){ o0[jj]=f2b(f[jj]*rinv*qnw[qd+jj]); o1[jj]=f2b(f[8+jj]*rinv*qnw[qd+8+jj]); }
    u16* dst = qO + ((size_t)bh*1024 + n0 + nr)*64 + qd;
    *(u16x8*)dst = o0; *(u16x8*)(dst+8) = o1;
  }
  // K: rms-norm * kn_w -> fragment-major
  {
    u16x8 a0 = *(const u16x8*)(rowp + 1024 + h*64 + qd);
    u16x8 a1 = *(const u16x8*)(rowp + 1024 + h*64 + qd + 8);
    float f[16]; float ss=0;
#pragma unroll
    for (int jj=0;jj<8;jj++){ f[jj]=b2f(a0[jj]); f[8+jj]=b2f(a1[jj]); }
#pragma unroll
    for (int jj=0;jj<16;jj++) ss += f[jj]*f[jj];
    ss += __shfl_xor(ss,1); ss += __shfl_xor(ss,2);
    float rinv = rsqrtf(ss*(1.f/64.f)+1e-6f);
    u16x8 o0,o1;
#pragma unroll
    for (int jj=0;jj<8;jj++){ o0[jj]=f2b(f[jj]*rinv*knw[qd+jj]); o1[jj]=f2b(f[8+jj]*rinv*knw[qd+8+jj]); }
    int t16 = (n0 + nr)>>4, lrk = nr&15;
    {
      int d0 = qd, c = d0>>5, lg = (d0>>3)&3;
      *(u16x8*)(kO + (size_t)bh*65536 + ((size_t)(t16*2+c)*64 + lg*16 + lrk)*8) = o0;
    }
    {
      int d0 = qd+8, c = d0>>5, lg = (d0>>3)&3;
      *(u16x8*)(kO + (size_t)bh*65536 + ((size_t)(t16*2+c)*64 + lg*16 + lrk)*8) = o1;
    }
  }
  // V: transpose via LDS, then write fragment-major
  {
    u16x8 a0 = *(const u16x8*)(rowp + 2048 + h*64 + qd);
    u16x8 a1 = *(const u16x8*)(rowp + 2048 + h*64 + qd + 8);
#pragma unroll
    for (int jj=0;jj<8;jj++){ ldsv[qd+jj][nr] = a0[jj]; ldsv[qd+8+jj][nr] = a1[jj]; }
  }
  __syncthreads();
  {
    int d = t>>2, ns = (t&3)*16;
    int tt = d>>4, lrv = d&15;
    int m = (n0 + ns)>>5;
    int hf = (ns>>4)&1;
    u16* basep = vO + (size_t)bh*65536 + ((size_t)(m*4+tt)*64 + lrv)*8 + hf*4;
#pragma unroll
    for (int g=0; g<4; ++g){
      u16x4 wv4 = { ldsv[d][ns+g*4], ldsv[d][ns+g*4+1], ldsv[d][ns+g*4+2], ldsv[d][ns+g*4+3] };
      *(u16x4*)(basep + (size_t)g*128) = wv4;
    }
  }
}

// ---------------- flash attention: split-K x2, coalesced fragment loads, defer-max, exp2 ----------------
__global__ __launch_bounds__(512) void attn_fwd(const u16* __restrict__ qO,
    const u16* __restrict__ kO, const u16* __restrict__ vO, u16* __restrict__ o)
{
  __shared__ __align__(16) float obuf[4][64][16];
  __shared__ __align__(16) float mlb[4][2][2][16];
  int bh = blockIdx.y, b = bh>>4, h = bh&15;
  int w = threadIdx.x>>6, lane = threadIdx.x&63;
  int pair = w>>1, half = w&1;
  int lr = lane&15, lg = lane>>4;
  int q0 = blockIdx.x*64 + pair*16;
  const u16* qp = qO + ((size_t)bh*1024 + q0 + lr)*64 + lg*8;
  bf16x8 qf0 = *(const bf16x8*)qp;
  bf16x8 qf1 = *(const bf16x8*)(qp + 32);
  const u16* kb = kO + (size_t)bh*65536 + (size_t)half*32768 + (size_t)lane*8;
  const u16* vb = vO + (size_t)bh*65536 + (size_t)half*32768 + (size_t)lane*8;
  f32x4 oacc[4] = {};
  float mrun = -3.0e38f, lrun = 0.f;
  for (int it=0; it<16; ++it){
    const u16* kp = kb + (size_t)it*4096;
    bf16x8 k00 = *(const bf16x8*)(kp);
    bf16x8 k01 = *(const bf16x8*)(kp + 512);
    bf16x8 k10 = *(const bf16x8*)(kp + 1024);
    bf16x8 k11 = *(const bf16x8*)(kp + 1536);
    f32x4 s0 = {}, s1 = {};
    s0 = mfma16(k00, qf0, s0); s0 = mfma16(k01, qf1, s0);
    s1 = mfma16(k10, qf0, s1); s1 = mfma16(k11, qf1, s1);
    const u16* vp = vb + (size_t)it*2048;
    bf16x8 vv[4];
#pragma unroll
    for (int tt=0;tt<4;tt++) vv[tt] = *(const bf16x8*)(vp + tt*512);
    float pm = fmaxf(fmaxf(fmaxf(s0[0],s0[1]),fmaxf(s0[2],s0[3])),
                     fmaxf(fmaxf(s1[0],s1[1]),fmaxf(s1[2],s1[3])));
    pm = fmaxf(pm, __shfl_xor(pm, 16));
    pm = fmaxf(pm, __shfl_xor(pm, 32));
    if (__any(pm > mrun + 8.f)){
      float mnew = fmaxf(mrun, pm);
      float alpha = fexp2(mrun - mnew);
      mrun = mnew;
      lrun *= alpha;
      float ar[4];
#pragma unroll
      for (int r=0;r<4;r++) ar[r] = __shfl(alpha, lg*4 + r);
#pragma unroll
      for (int tt=0;tt<4;tt++)
#pragma unroll
        for (int r=0;r<4;r++) oacc[tt][r] *= ar[r];
    }
    float p0[4], p1[4]; float ls = 0.f;
#pragma unroll
    for (int r=0;r<4;r++){ p0[r]=fexp2(s0[r]-mrun); p1[r]=fexp2(s1[r]-mrun); ls += p0[r]+p1[r]; }
    ls += __shfl_xor(ls, 16); ls += __shfl_xor(ls, 32);
    lrun += ls;
    bf16x4 pa0, pa1;
#pragma unroll
    for (int r=0;r<4;r++){ pa0[r] = (__bf16)p0[r]; pa1[r] = (__bf16)p1[r]; }
#pragma unroll
    for (int tt=0;tt<4;tt++){
      bf16x4* vh = (bf16x4*)&vv[tt];
      oacc[tt] = mfma16k16(pa0, vh[0], oacc[tt]);
      oacc[tt] = mfma16k16(pa1, vh[1], oacc[tt]);
    }
  }
  if (lg==0){ mlb[pair][half][0][lr] = mrun; mlb[pair][half][1][lr] = lrun; }
  __syncthreads();
  f32x4 m0 = *(const f32x4*)&mlb[pair][0][0][lg*4];
  f32x4 l0 = *(const f32x4*)&mlb[pair][0][1][lg*4];
  f32x4 m1 = *(const f32x4*)&mlb[pair][1][0][lg*4];
  f32x4 l1 = *(const f32x4*)&mlb[pair][1][1][lg*4];
  f32x4 fh;
#pragma unroll
  for (int r=0;r<4;r++){
    float m = fmaxf(m0[r], m1[r]);
    float e0 = fexp2(m0[r]-m), e1 = fexp2(m1[r]-m);
    float li = 1.f/(l0[r]*e0 + l1[r]*e1);
    fh[r] = (half ? e1 : e0)*li;
  }
  if (half==1){
#pragma unroll
    for (int tt=0;tt<4;tt++){
      f32x4 tv;
#pragma unroll
      for (int r=0;r<4;r++) tv[r] = oacc[tt][r]*fh[r];
      *(f32x4*)&obuf[pair][lane][tt*4] = tv;
    }
  }
  __syncthreads();
  if (half==0){
#pragma unroll
    for (int tt=0;tt<4;tt++){
      f32x4 p = *(const f32x4*)&obuf[pair][lane][tt*4];
#pragma unroll
      for (int r=0;r<4;r++){
        int row = (b<<10) + q0 + lg*4 + r;
        int col = h*64 + tt*16 + lr;
        o[(size_t)row*1024 + col] = f2b(oacc[tt][r]*fh[r] + p[r]);
      }
    }
  }
}

// ---------------- SwiGLU: hid = silu(x1)*x2, zero-padded to 2752 cols ----------------
__global__ __launch_bounds__(256) void swiglu_k(const u16* __restrict__ x12, u16* __restrict__ hid)
{
  int r = blockIdx.y;
  int c4 = blockIdx.x*256 + threadIdx.x;
  if (c4 >= 688) return;
  int cc = c4*4;
  const u16* rowp = x12 + (size_t)r*5632;
  u16x4 x1 = *(const u16x4*)(rowp + cc);
  u16x2 x2a = *(const u16x2*)(rowp + 2730 + cc);
  u16x2 x2b = *(const u16x2*)(rowp + 2730 + cc + 2);
  u16 x2v[4] = {x2a[0],x2a[1],x2b[0],x2b[1]};
  u16x4 o;
#pragma unroll
  for (int jj=0;jj<4;jj++){
    float a = b2f(x1[jj]);
    float g = silu_f(a)*b2f(x2v[jj]);
    o[jj] = (cc+jj < 2730) ? f2b(g) : (u16)0;
  }
  *(u16x4*)&hid[(size_t)r*2752 + cc] = o;
}

extern "C" void kernel_launch(void* const* d_in, const int* in_sizes, int n_in,
                              void* d_out, int out_size, void* d_ws, size_t ws_size,
                              hipStream_t stream)
{
  (void)in_sizes; (void)n_in; (void)out_size; (void)ws_size;
  const float* x    = (const float*)d_in[0];
  const float* c    = (const float*)d_in[1];
  const float* n1w  = (const float*)d_in[2];
  const float* cw   = (const float*)d_in[3];
  const float* cb   = (const float*)d_in[4];
  const float* qkvw = (const float*)d_in[5];
  const float* qkvb = (const float*)d_in[6];
  const float* qnw  = (const float*)d_in[7];
  const float* knw  = (const float*)d_in[8];
  const float* pw   = (const float*)d_in[9];
  const float* pb   = (const float*)d_in[10];
  const float* ew   = (const float*)d_in[11];
  const float* eb   = (const float*)d_in[12];
  const float* n2w  = (const float*)d_in[13];
  const float* w12w = (const float*)d_in[14];
  const float* w12b = (const float*)d_in[15];
  const float* w3w  = (const float*)d_in[16];
  const float* w3b  = (const float*)d_in[17];
  const float* adaw = (const float*)d_in[18];
  const float* adab = (const float*)d_in[19];
  float* out = (float*)d_out;
  char* ws = (char*)d_ws;
  auto U = [&](size_t off){ return (u16*)(ws + off); };
  auto F = [&](size_t off){ return (float*)(ws + off); };

  // weight conversions (bf16, zero-padded)
  convert_pad<<<dim3(1,1024), 256, 0, stream>>>(cw,   U(OFF_WC),   1024, 1024, 1024);
  convert_pad<<<dim3(1,3072), 256, 0, stream>>>(qkvw, U(OFF_WQKV), 3072, 1024, 1024);
  convert_pad<<<dim3(1,1024), 256, 0, stream>>>(pw,   U(OFF_WPROJ),1024, 1024, 1024);
  convert_pad<<<dim3(1,1024), 256, 0, stream>>>(ew,   U(OFF_WEXP), 1024, 1024, 1024);
  convert_pad<<<dim3(1,5632), 256, 0, stream>>>(w12w, U(OFF_WW12), 5460, 1024, 1024);
  convert_pad<<<dim3(3,1024), 256, 0, stream>>>(w3w,  U(OFF_WW3),  1024, 2730, 2752);

  ada_kernel<<<1536, 256, 0, stream>>>(c, adaw, adab, F(OFF_ADA));

  // attention branch
  rms_mod<<<4096, 256, 0, stream>>>(x, n1w, F(OFF_ADA), 0, U(OFF_H1));
  gemm_dr<0><<<dim3(8,32), 256, 0, stream>>>(U(OFF_H1), U(OFF_WC), cb, 1024, 1024, 1024, U(OFF_HC), nullptr, nullptr, 0, nullptr);
  gemm_dr<0><<<dim3(24,32), 256, 0, stream>>>(U(OFF_HC), U(OFF_WQKV), qkvb, 3072, 1024, 3072, U(OFF_QKVO), nullptr, nullptr, 0, nullptr);
  repack_qkv<<<dim3(16,64), 256, 0, stream>>>(U(OFF_QKVO), qnw, knw, U(OFF_Q), U(OFF_K), U(OFF_VT));
  attn_fwd<<<dim3(16,64), 512, 0, stream>>>(U(OFF_Q), U(OFF_K), U(OFF_VT), U(OFF_O));
  gemm_dr<0><<<dim3(8,32), 256, 0, stream>>>(U(OFF_O), U(OFF_WPROJ), pb, 1024, 1024, 1024, U(OFF_PR), nullptr, nullptr, 0, nullptr);
  gemm_dr<1><<<dim3(8,32), 256, 0, stream>>>(U(OFF_PR), U(OFF_WEXP), eb, 1024, 1024, 1024, nullptr, x, F(OFF_ADA), 2, F(OFF_X2));

  // FFN branch
  rms_mod<<<4096, 256, 0, stream>>>(F(OFF_X2), n2w, F(OFF_ADA), 3, U(OFF_H2));
  gemm_dr<0><<<dim3(44,32), 256, 0, stream>>>(U(OFF_H2), U(OFF_WW12), w12b, 5632, 1024, 5460, U(OFF_X12), nullptr, nullptr, 0, nullptr);
  swiglu_k<<<dim3(3,4096), 256, 0, stream>>>(U(OFF_X12), U(OFF_HID));
  gemm_dr<1><<<dim3(8,32), 256, 0, stream>>>(U(OFF_HID), U(OFF_WW3), w3b, 1024, 2752, 1024, nullptr, F(OFF_X2), F(OFF_ADA), 5, out);
}

// Round 10
// 305.906 us; speedup vs baseline: 1.0675x; 1.0675x over previous
//
#include <hip/hip_runtime.h>
#include <hip/hip_bf16.h>
#include <cstdint>
#include <cstddef>

typedef unsigned short u16;
typedef __bf16 bf16x8 __attribute__((ext_vector_type(8)));
typedef __bf16 bf16x4 __attribute__((ext_vector_type(4)));
typedef short   s16x4 __attribute__((ext_vector_type(4)));
typedef float    f32x4 __attribute__((ext_vector_type(4)));
typedef unsigned short u16x2 __attribute__((ext_vector_type(2)));
typedef unsigned short u16x4 __attribute__((ext_vector_type(4)));
typedef unsigned short u16x8 __attribute__((ext_vector_type(8)));

#define DEVI static __device__ __forceinline__

DEVI float b2f(u16 u){ union{unsigned i; float v;} x; x.i=((unsigned)u)<<16; return x.v; }
DEVI u16 f2b(float f){ union{float v; unsigned i;} x; x.v=f; unsigned r=x.i+0x7FFFu+((x.i>>16)&1u); return (u16)(r>>16); }
DEVI f32x4 mfma16(bf16x8 a, bf16x8 b, f32x4 c){ return __builtin_amdgcn_mfma_f32_16x16x32_bf16(a,b,c,0,0,0); }
DEVI f32x4 mfma16k16(bf16x4 a, bf16x4 b, f32x4 c){
#if __has_builtin(__builtin_amdgcn_mfma_f32_16x16x16_bf16)
  return __builtin_amdgcn_mfma_f32_16x16x16_bf16(a,b,c,0,0,0);
#elif __has_builtin(__builtin_amdgcn_mfma_f32_16x16x16bf16_1k)
  return __builtin_amdgcn_mfma_f32_16x16x16bf16_1k((s16x4)a,(s16x4)b,c,0,0,0);
#else
  asm volatile("v_mfma_f32_16x16x16_bf16 %0, %1, %2, %0" : "+v"(c) : "v"(a), "v"(b));
  return c;
#endif
}
DEVI float fexp2(float x){ return __builtin_amdgcn_exp2f(x); }
DEVI void gload16(const void* g, void* l){
  __builtin_amdgcn_global_load_lds((const __attribute__((address_space(1))) void*)g,
                                   (__attribute__((address_space(3))) void*)l, 16, 0, 0);
}
DEVI float silu_f(float x){ return x/(1.f+__expf(-x)); }

// ---------------- workspace layout (bytes) ----------------
static constexpr size_t OFF_WC   = 0;
static constexpr size_t OFF_WQKV = OFF_WC   + (size_t)1024*1024*2;
static constexpr size_t OFF_WPROJ= OFF_WQKV + (size_t)3072*1024*2;
static constexpr size_t OFF_WEXP = OFF_WPROJ+ (size_t)1024*1024*2;
static constexpr size_t OFF_WW12 = OFF_WEXP + (size_t)1024*1024*2;   // interleaved [5632][1024]
static constexpr size_t OFF_WW3  = OFF_WW12 + (size_t)5632*1024*2;
static constexpr size_t OFF_ADA  = OFF_WW3  + (size_t)1024*2752*2;
static constexpr size_t OFF_X2   = OFF_ADA  + (size_t)4*6144*4;
static constexpr size_t OFF_P1   = OFF_X2   + (size_t)4096*1024*4;
static constexpr size_t OFF_H1   = OFF_P1;
static constexpr size_t OFF_HC   = OFF_H1   + (size_t)4096*1024*2;
static constexpr size_t OFF_QKVO = OFF_HC   + (size_t)4096*1024*2;
static constexpr size_t OFF_P2   = OFF_P1   + (size_t)4096*5632*2;
static constexpr size_t OFF_Q    = OFF_P2;
static constexpr size_t OFF_K    = OFF_Q    + (size_t)64*1024*64*2;
static constexpr size_t OFF_VT   = OFF_K    + (size_t)64*1024*64*2;
static constexpr size_t OFF_O    = OFF_VT   + (size_t)64*1024*64*2;
static constexpr size_t OFF_PR   = OFF_O    + (size_t)4096*1024*2;
static constexpr size_t OFF_H2   = OFF_PR   + (size_t)4096*1024*2;
static constexpr size_t OFF_HID  = OFF_P2;                       // [4096][2752] bf16 (reuse: q/k/vt dead)

// ---------------- fp32 -> bf16 weight conversion with zero padding ----------------
__global__ __launch_bounds__(256) void convert_pad(const float* __restrict__ src, u16* __restrict__ dst,
                                                   int R, int C, int Cpad)
{
  int r = blockIdx.y;
  int c0 = (blockIdx.x*256 + threadIdx.x)*4;
  if (c0 >= Cpad) return;
  u16x4 o;
#pragma unroll
  for (int j=0;j<4;j++){
    int cc = c0+j;
    float f = (r < R && cc < C) ? src[(size_t)r*C + cc] : 0.f;
    o[j] = f2b(f);
  }
  *(u16x4*)&dst[(size_t)r*Cpad + c0] = o;
}

// ---------------- w12 interleaved convert: row r' -> group g=r'>>4, w=r'&15 ----------------
// w<8: w1 row g*8+w ; w>=8: w2 row 2730 + g*8 + (w-8). Zero-pad beyond 2730.
__global__ __launch_bounds__(256) void convert_w12i(const float* __restrict__ src, u16* __restrict__ dst)
{
  int rp = blockIdx.y;
  int c0 = threadIdx.x*4;
  int g = rp>>4, w = rp&15;
  int sr = g*8 + (w&7);
  bool valid = sr < 2730;
  int srow = (w<8) ? sr : 2730 + sr;
  u16x4 o;
#pragma unroll
  for (int j=0;j<4;j++){
    float f = valid ? src[(size_t)srow*1024 + c0 + j] : 0.f;
    o[j] = f2b(f);
  }
  *(u16x4*)&dst[(size_t)rp*1024 + c0] = o;
}

// ---------------- adaLN: ada = silu(c) @ ada_w.T + ada_b  -> [4][6144] fp32 ----------------
__global__ __launch_bounds__(256) void ada_kernel(const float* __restrict__ c,
    const float* __restrict__ aw, const float* __restrict__ ab, float* __restrict__ ada)
{
  __shared__ float s[4][1024];
  int t = threadIdx.x;
#pragma unroll
  for (int i=0;i<16;i++){
    int idx = i*256 + t;
    float cv = c[idx];
    s[idx>>10][idx&1023] = cv/(1.f+__expf(-cv));
  }
  __syncthreads();
  int wid = t>>6, lane = t&63;
  int j = blockIdx.x*4 + wid;
  const f32x4* wp = (const f32x4*)(aw + (size_t)j*1024);
  float a0=0,a1=0,a2=0,a3=0;
#pragma unroll
  for (int i=0;i<4;i++){
    f32x4 wv = wp[i*64 + lane];
    int k0 = (i*64+lane)*4;
#pragma unroll
    for (int e=0;e<4;e++){
      float w = wv[e];
      a0 += w*s[0][k0+e]; a1 += w*s[1][k0+e]; a2 += w*s[2][k0+e]; a3 += w*s[3][k0+e];
    }
  }
#pragma unroll
  for (int mask=1; mask<64; mask<<=1){
    a0 += __shfl_xor(a0, mask); a1 += __shfl_xor(a1, mask);
    a2 += __shfl_xor(a2, mask); a3 += __shfl_xor(a3, mask);
  }
  if (lane==0){
    float bv = ab[j];
    ada[0*6144 + j] = a0 + bv;
    ada[1*6144 + j] = a1 + bv;
    ada[2*6144 + j] = a2 + bv;
    ada[3*6144 + j] = a3 + bv;
  }
}

// ---------------- fused RMSNorm + modulate -> bf16 ----------------
__global__ __launch_bounds__(256) void rms_mod(const float* __restrict__ x,
    const float* __restrict__ w, const float* __restrict__ ada, int chunkSh,
    u16* __restrict__ out)
{
  int row = blockIdx.x;
  int b = row>>10;
  int t = threadIdx.x;
  int wid = t>>6, lane = t&63;
  f32x4 v = *(const f32x4*)(x + (size_t)row*1024 + t*4);
  float ss = v[0]*v[0]+v[1]*v[1]+v[2]*v[2]+v[3]*v[3];
#pragma unroll
  for (int mask=1; mask<64; mask<<=1) ss += __shfl_xor(ss, mask);
  __shared__ float red[4];
  if (lane==0) red[wid]=ss;
  __syncthreads();
  float rinv = rsqrtf((red[0]+red[1]+red[2]+red[3])*(1.f/1024.f) + 1e-6f);
  int cc = t*4;
  const float* shp = ada + (size_t)b*6144 + (size_t)chunkSh*1024 + cc;
  u16x4 o;
#pragma unroll
  for (int jj=0;jj<4;jj++){
    float val = v[jj]*rinv*w[cc+jj];
    val = val*(1.f+shp[jj+1024]) + shp[jj];
    o[jj] = f2b(val);
  }
  *(u16x4*)&out[(size_t)row*1024 + cc] = o;
}

// ---------------- bf16 GEMM 128x128 (BK=32), ring-6 LDS, depth-5 counted-vmcnt pipeline ----------------
// Grid exactly (8,32): XCD-aware remap so each XCD owns 4 contiguous A-stripes.
// Swizzle f(row) = (row>>1)&3  (dp2's measured-conflict-free pattern).
template<int EPI>
__global__ __launch_bounds__(256) void gemm_dr(
    const u16* __restrict__ A, const u16* __restrict__ Bw, const float* __restrict__ bias,
    int N, int K, int nbias, u16* __restrict__ outb,
    const float* __restrict__ xres, const float* __restrict__ ada, int adaChunk,
    float* __restrict__ outf)
{
  constexpr int RU = 8192;                 // (128 A-rows + 128 B-rows) * 32 u16
  __shared__ __align__(16) u16 lds[6*RU];  // 96 KB
  int t = threadIdx.x;
  int lane = t&63, w = t>>6;
  int wr = (w>>1)*64, wc = (w&1)*64;
  int lr = lane&15, lg = lane>>4;
  // XCD remap (grid is 8 x 32 = 256 blocks, 32 per XCD)
  int id = blockIdx.y*8 + blockIdx.x;
  int xcd = id&7, loc = id>>3;
  int bm = xcd*4 + (loc>>3);
  int bn = loc&7;
  int srow = t>>2;
  int schunk = ((t&3) ^ ((t>>3)&3))*8;     // pre-swizzled global source chunk, f(row)=(row>>1)&3
  const u16* pA = A  + (size_t)(bm*128 + srow)*K + schunk;
  const u16* pB = Bw + (size_t)(bn*128 + srow)*K + schunk;
  int rp = (lg ^ ((lr>>1)&3))*8;           // swizzled read position
  int aoff = (wr + lr)*32 + rp;
  int boff = 4096 + (wc + lr)*32 + rp;
  f32x4 acc[4][4] = {};
  int NT = K>>5;

  auto stage = [&](int kt, int slot){
    u16* dst = &lds[slot*RU];
    const u16* sa = pA + (size_t)kt*32;
    const u16* sb = pB + (size_t)kt*32;
    gload16(sa,                dst + t*8);
    gload16(sa + (size_t)64*K, dst + 2048 + t*8);
    gload16(sb,                dst + 4096 + t*8);
    gload16(sb + (size_t)64*K, dst + 6144 + t*8);
  };
  auto compute = [&](int slot){
    const u16* lb = &lds[slot*RU];
    bf16x8 af[4], bfr[4];
#pragma unroll
    for (int m=0;m<4;m++) af[m]  = *(const bf16x8*)&lb[aoff + m*512];
#pragma unroll
    for (int n=0;n<4;n++) bfr[n] = *(const bf16x8*)&lb[boff + n*512];
    __builtin_amdgcn_s_setprio(1);
#pragma unroll
    for (int m=0;m<4;m++)
#pragma unroll
      for (int n=0;n<4;n++)
        acc[m][n] = mfma16(af[m], bfr[n], acc[m][n]);
    __builtin_amdgcn_s_setprio(0);
  };

  // prologue: stage tiles 0..4 into slots 0..4 (20 loads in flight)
#pragma unroll
  for (int i=0;i<5;i++) stage(i, i);
  asm volatile("s_waitcnt vmcnt(16)" ::: "memory");   // tile 0 ready
  __builtin_amdgcn_s_barrier();
  __builtin_amdgcn_sched_barrier(0);

  int cur = 0, stg = 5;
  for (int kt=0; kt<NT-5; ++kt){
    stage(kt+5, stg);
    compute(cur);
    asm volatile("s_waitcnt vmcnt(16)" ::: "memory"); // next tile ready, 16 stay in flight
    __builtin_amdgcn_s_barrier();
    __builtin_amdgcn_sched_barrier(0);
    cur = (cur==5)?0:cur+1;
    stg = (stg==5)?0:stg+1;
  }
  // tail: 5 tiles, drain 16 -> 12 -> 8 -> 4 -> 0
  compute(cur); cur=(cur==5)?0:cur+1;
  asm volatile("s_waitcnt vmcnt(12)" ::: "memory");
  __builtin_amdgcn_s_barrier(); __builtin_amdgcn_sched_barrier(0);
  compute(cur); cur=(cur==5)?0:cur+1;
  asm volatile("s_waitcnt vmcnt(8)" ::: "memory");
  __builtin_amdgcn_s_barrier(); __builtin_amdgcn_sched_barrier(0);
  compute(cur); cur=(cur==5)?0:cur+1;
  asm volatile("s_waitcnt vmcnt(4)" ::: "memory");
  __builtin_amdgcn_s_barrier(); __builtin_amdgcn_sched_barrier(0);
  compute(cur); cur=(cur==5)?0:cur+1;
  asm volatile("s_waitcnt vmcnt(0)" ::: "memory");
  __builtin_amdgcn_s_barrier(); __builtin_amdgcn_sched_barrier(0);
  compute(cur);

#pragma unroll
  for (int n=0;n<4;n++){
    int col = bn*128 + wc + n*16 + lr;
    float bv = (col < nbias) ? bias[col] : 0.f;
#pragma unroll
    for (int m=0;m<4;m++){
      int row0 = bm*128 + wr + m*16 + lg*4;
#pragma unroll
      for (int r=0;r<4;r++){
        int row = row0 + r;
        float v = acc[m][n][r] + bv;
        if constexpr (EPI==0){
          outb[(size_t)row*N + col] = f2b(v);
        } else {
          int bb = row>>10;
          float g = ada[(size_t)bb*6144 + (size_t)adaChunk*1024 + col];
          outf[(size_t)row*1024 + col] = xres[(size_t)row*1024 + col] + g*v;
        }
      }
    }
  }
}

// ---------------- bf16 GEMM 128x256 (BK=32), 4 waves, ring-3, counted vmcnt ----------------
// EPI 0: bf16 out ld=N. EPI 2: fused SwiGLU with interleaved B (pairs via shfl_xor 8) -> hid ld=2752.
template<int EPI>
__global__ __launch_bounds__(256,2) void gemm_dp2(
    const u16* __restrict__ A, const u16* __restrict__ Bw, const float* __restrict__ bias,
    int N, int K, int nbias, u16* __restrict__ outb)
{
  constexpr int AU = 128*32;          // 4096 u16
  constexpr int RU = AU + 256*32;     // 12288 u16 = 24KB
  __shared__ __align__(16) u16 lds[3*RU];
  int t = threadIdx.x;
  int lane = t&63, w = t>>6;
  int wr = w>>1, wc = w&1;            // 2x2 wave grid, wave tile 64x128
  int lr = lane&15, lg = lane>>4;
  int bm = blockIdx.y, bn = blockIdx.x;
  int schunk = ((t&3) ^ ((t>>3)&3))*8;
  const u16* pA = A  + (size_t)(bm*128 + (t>>2))*K + schunk;
  const u16* pB = Bw + (size_t)(bn*256 + (t>>2))*K + schunk;
  int rsw  = (lg ^ ((lr>>1)&3))*8;
  int aoff = (wr*64 + lr)*32 + rsw;
  int boff = AU + (wc*128 + lr)*32 + rsw;
  f32x4 acc[4][8] = {};
  int NT = K>>5;

  auto stage = [&](int kt, int rg){
    u16* dst = &lds[rg*RU];
    const u16* sa = pA + (size_t)kt*32;
    const u16* sb = pB + (size_t)kt*32;
    gload16(sa,                  dst + t*8);
    gload16(sa + (size_t)64*K,   dst + 2048 + t*8);
#pragma unroll
    for (int i=0;i<4;i++)
      gload16(sb + (size_t)(i*64)*K, dst + AU + i*2048 + t*8);
  };

  stage(0, 0);
  stage(1, 1);
  asm volatile("s_waitcnt vmcnt(6)" ::: "memory");
  __builtin_amdgcn_s_barrier();
  __builtin_amdgcn_sched_barrier(0);

  int cur = 0, stg = 2;
  for (int kt=0; kt<NT; ++kt){
    const u16* lb = &lds[cur*RU];
    if (kt+2 < NT) stage(kt+2, stg);
    bf16x8 af[4], bfr[8];
#pragma unroll
    for (int mf=0;mf<4;mf++) af[mf] = *(const bf16x8*)&lb[aoff + mf*512];
#pragma unroll
    for (int nf=0;nf<8;nf++) bfr[nf] = *(const bf16x8*)&lb[boff + nf*512];
    __builtin_amdgcn_s_setprio(1);
#pragma unroll
    for (int mf=0;mf<4;mf++)
#pragma unroll
      for (int nf=0;nf<8;nf++)
        acc[mf][nf] = mfma16(af[mf], bfr[nf], acc[mf][nf]);
    __builtin_amdgcn_s_setprio(0);
    if (kt+2 < NT){
      asm volatile("s_waitcnt vmcnt(6)" ::: "memory");
    } else if (kt+1 < NT){
      asm volatile("s_waitcnt vmcnt(0)" ::: "memory");
    }
    if (kt+1 < NT){
      __builtin_amdgcn_s_barrier();
      __builtin_amdgcn_sched_barrier(0);
    }
    cur = (cur==2)?0:cur+1;
    stg = (stg==2)?0:stg+1;
  }
  if constexpr (EPI==0){
#pragma unroll
    for (int nf=0;nf<8;nf++){
      int col = bn*256 + wc*128 + nf*16 + lr;
      float bv = (col < nbias) ? bias[col] : 0.f;
#pragma unroll
      for (int mf=0; mf<4; mf++){
        int row0 = bm*128 + wr*64 + mf*16 + lg*4;
#pragma unroll
        for (int r=0;r<4;r++)
          outb[(size_t)(row0+r)*N + col] = f2b(acc[mf][nf][r] + bv);
      }
    }
  } else {
    // fused SwiGLU: local col L = wc*128+nf*16+lr; pair index P = bn*128 + (wc*8+nf)*8 + (lr&7)
    // lanes lr<8 hold x1, lr>=8 hold x2 of the same pair (B rows interleaved by convert_w12i).
    bool x1lane = (lr&8)==0;
#pragma unroll
    for (int nf=0;nf<8;nf++){
      int P = bn*128 + (wc*8+nf)*8 + (lr&7);
      bool vP = (P < 2730);
      float bv = vP ? bias[x1lane ? P : 2730+P] : 0.f;
#pragma unroll
      for (int mf=0; mf<4; mf++){
        int row0 = bm*128 + wr*64 + mf*16 + lg*4;
#pragma unroll
        for (int r=0;r<4;r++){
          float v = acc[mf][nf][r] + bv;
          float pv = __shfl_xor(v, 8);
          float x1 = x1lane ? v : pv;
          float x2 = x1lane ? pv : v;
          if (x1lane && vP){
            float gv = silu_f(x1)*x2;
            outb[(size_t)(row0+r)*2752 + P] = f2b(gv);
          }
        }
      }
    }
  }
}

// ---------------- qkv repack: rms-norm q,k per head, fragment-major K/V for attention ----------------
__global__ __launch_bounds__(256) void repack_qkv(const u16* __restrict__ qkvO,
    const float* __restrict__ qnw, const float* __restrict__ knw,
    u16* __restrict__ qO, u16* __restrict__ kO, u16* __restrict__ vO)
{
  __shared__ u16 ldsv[64][64];
  int bh = blockIdx.y, b = bh>>4, h = bh&15;
  int n0 = blockIdx.x*64;
  int t = threadIdx.x;
  int nr = t>>2, qd = (t&3)*16;
  const u16* rowp = qkvO + (size_t)(b*1024 + n0 + nr)*3072;
  // Q: rms-norm * qn_w * (1/8)*log2e
  {
    u16x8 a0 = *(const u16x8*)(rowp + h*64 + qd);
    u16x8 a1 = *(const u16x8*)(rowp + h*64 + qd + 8);
    float f[16]; float ss=0;
#pragma unroll
    for (int jj=0;jj<8;jj++){ f[jj]=b2f(a0[jj]); f[8+jj]=b2f(a1[jj]); }
#pragma unroll
    for (int jj=0;jj<16;jj++) ss += f[jj]*f[jj];
    ss += __shfl_xor(ss,1); ss += __shfl_xor(ss,2);
    float rinv = rsqrtf(ss*(1.f/64.f)+1e-6f)*0.125f*1.44269504089f;
    u16x8 o0,o1;
#pragma unroll
    for (int jj=0;jj<8;jj++){ o0[jj]=f2b(f[jj]*rinv*qnw[qd+jj]); o1[jj]=f2b(f[8+jj]*rinv*qnw[qd+8+jj]); }
    u16* dst = qO + ((size_t)bh*1024 + n0 + nr)*64 + qd;
    *(u16x8*)dst = o0; *(u16x8*)(dst+8) = o1;
  }
  // K: rms-norm * kn_w -> fragment-major
  {
    u16x8 a0 = *(const u16x8*)(rowp + 1024 + h*64 + qd);
    u16x8 a1 = *(const u16x8*)(rowp + 1024 + h*64 + qd + 8);
    float f[16]; float ss=0;
#pragma unroll
    for (int jj=0;jj<8;jj++){ f[jj]=b2f(a0[jj]); f[8+jj]=b2f(a1[jj]); }
#pragma unroll
    for (int jj=0;jj<16;jj++) ss += f[jj]*f[jj];
    ss += __shfl_xor(ss,1); ss += __shfl_xor(ss,2);
    float rinv = rsqrtf(ss*(1.f/64.f)+1e-6f);
    u16x8 o0,o1;
#pragma unroll
    for (int jj=0;jj<8;jj++){ o0[jj]=f2b(f[jj]*rinv*knw[qd+jj]); o1[jj]=f2b(f[8+jj]*rinv*knw[qd+8+jj]); }
    int t16 = (n0 + nr)>>4, lrk = nr&15;
    {
      int d0 = qd, c = d0>>5, lg = (d0>>3)&3;
      *(u16x8*)(kO + (size_t)bh*65536 + ((size_t)(t16*2+c)*64 + lg*16 + lrk)*8) = o0;
    }
    {
      int d0 = qd+8, c = d0>>5, lg = (d0>>3)&3;
      *(u16x8*)(kO + (size_t)bh*65536 + ((size_t)(t16*2+c)*64 + lg*16 + lrk)*8) = o1;
    }
  }
  // V: transpose via LDS, then write fragment-major
  {
    u16x8 a0 = *(const u16x8*)(rowp + 2048 + h*64 + qd);
    u16x8 a1 = *(const u16x8*)(rowp + 2048 + h*64 + qd + 8);
#pragma unroll
    for (int jj=0;jj<8;jj++){ ldsv[qd+jj][nr] = a0[jj]; ldsv[qd+8+jj][nr] = a1[jj]; }
  }
  __syncthreads();
  {
    int d = t>>2, ns = (t&3)*16;
    int tt = d>>4, lrv = d&15;
    int m = (n0 + ns)>>5;
    int hf = (ns>>4)&1;
    u16* basep = vO + (size_t)bh*65536 + ((size_t)(m*4+tt)*64 + lrv)*8 + hf*4;
#pragma unroll
    for (int g=0; g<4; ++g){
      u16x4 wv4 = { ldsv[d][ns+g*4], ldsv[d][ns+g*4+1], ldsv[d][ns+g*4+2], ldsv[d][ns+g*4+3] };
      *(u16x4*)(basep + (size_t)g*128) = wv4;
    }
  }
}

// ---------------- flash attention: split-K x2, coalesced fragment loads, defer-max, exp2 ----------------
__global__ __launch_bounds__(512) void attn_fwd(const u16* __restrict__ qO,
    const u16* __restrict__ kO, const u16* __restrict__ vO, u16* __restrict__ o)
{
  __shared__ __align__(16) float obuf[4][64][16];
  __shared__ __align__(16) float mlb[4][2][2][16];
  int bh = blockIdx.y, b = bh>>4, h = bh&15;
  int w = threadIdx.x>>6, lane = threadIdx.x&63;
  int pair = w>>1, half = w&1;
  int lr = lane&15, lg = lane>>4;
  int q0 = blockIdx.x*64 + pair*16;
  const u16* qp = qO + ((size_t)bh*1024 + q0 + lr)*64 + lg*8;
  bf16x8 qf0 = *(const bf16x8*)qp;
  bf16x8 qf1 = *(const bf16x8*)(qp + 32);
  const u16* kb = kO + (size_t)bh*65536 + (size_t)half*32768 + (size_t)lane*8;
  const u16* vb = vO + (size_t)bh*65536 + (size_t)half*32768 + (size_t)lane*8;
  f32x4 oacc[4] = {};
  float mrun = -3.0e38f, lrun = 0.f;
  for (int it=0; it<16; ++it){
    const u16* kp = kb + (size_t)it*4096;
    bf16x8 k00 = *(const bf16x8*)(kp);
    bf16x8 k01 = *(const bf16x8*)(kp + 512);
    bf16x8 k10 = *(const bf16x8*)(kp + 1024);
    bf16x8 k11 = *(const bf16x8*)(kp + 1536);
    f32x4 s0 = {}, s1 = {};
    s0 = mfma16(k00, qf0, s0); s0 = mfma16(k01, qf1, s0);
    s1 = mfma16(k10, qf0, s1); s1 = mfma16(k11, qf1, s1);
    const u16* vp = vb + (size_t)it*2048;
    bf16x8 vv[4];
#pragma unroll
    for (int tt=0;tt<4;tt++) vv[tt] = *(const bf16x8*)(vp + tt*512);
    float pm = fmaxf(fmaxf(fmaxf(s0[0],s0[1]),fmaxf(s0[2],s0[3])),
                     fmaxf(fmaxf(s1[0],s1[1]),fmaxf(s1[2],s1[3])));
    pm = fmaxf(pm, __shfl_xor(pm, 16));
    pm = fmaxf(pm, __shfl_xor(pm, 32));
    if (__any(pm > mrun + 8.f)){
      float mnew = fmaxf(mrun, pm);
      float alpha = fexp2(mrun - mnew);
      mrun = mnew;
      lrun *= alpha;
      float ar[4];
#pragma unroll
      for (int r=0;r<4;r++) ar[r] = __shfl(alpha, lg*4 + r);
#pragma unroll
      for (int tt=0;tt<4;tt++)
#pragma unroll
        for (int r=0;r<4;r++) oacc[tt][r] *= ar[r];
    }
    float p0[4], p1[4]; float ls = 0.f;
#pragma unroll
    for (int r=0;r<4;r++){ p0[r]=fexp2(s0[r]-mrun); p1[r]=fexp2(s1[r]-mrun); ls += p0[r]+p1[r]; }
    ls += __shfl_xor(ls, 16); ls += __shfl_xor(ls, 32);
    lrun += ls;
    bf16x4 pa0, pa1;
#pragma unroll
    for (int r=0;r<4;r++){ pa0[r] = (__bf16)p0[r]; pa1[r] = (__bf16)p1[r]; }
#pragma unroll
    for (int tt=0;tt<4;tt++){
      bf16x4* vh = (bf16x4*)&vv[tt];
      oacc[tt] = mfma16k16(pa0, vh[0], oacc[tt]);
      oacc[tt] = mfma16k16(pa1, vh[1], oacc[tt]);
    }
  }
  if (lg==0){ mlb[pair][half][0][lr] = mrun; mlb[pair][half][1][lr] = lrun; }
  __syncthreads();
  f32x4 m0 = *(const f32x4*)&mlb[pair][0][0][lg*4];
  f32x4 l0 = *(const f32x4*)&mlb[pair][0][1][lg*4];
  f32x4 m1 = *(const f32x4*)&mlb[pair][1][0][lg*4];
  f32x4 l1 = *(const f32x4*)&mlb[pair][1][1][lg*4];
  f32x4 fh;
#pragma unroll
  for (int r=0;r<4;r++){
    float m = fmaxf(m0[r], m1[r]);
    float e0 = fexp2(m0[r]-m), e1 = fexp2(m1[r]-m);
    float li = 1.f/(l0[r]*e0 + l1[r]*e1);
    fh[r] = (half ? e1 : e0)*li;
  }
  if (half==1){
#pragma unroll
    for (int tt=0;tt<4;tt++){
      f32x4 tv;
#pragma unroll
      for (int r=0;r<4;r++) tv[r] = oacc[tt][r]*fh[r];
      *(f32x4*)&obuf[pair][lane][tt*4] = tv;
    }
  }
  __syncthreads();
  if (half==0){
#pragma unroll
    for (int tt=0;tt<4;tt++){
      f32x4 p = *(const f32x4*)&obuf[pair][lane][tt*4];
#pragma unroll
      for (int r=0;r<4;r++){
        int row = (b<<10) + q0 + lg*4 + r;
        int col = h*64 + tt*16 + lr;
        o[(size_t)row*1024 + col] = f2b(oacc[tt][r]*fh[r] + p[r]);
      }
    }
  }
}

extern "C" void kernel_launch(void* const* d_in, const int* in_sizes, int n_in,
                              void* d_out, int out_size, void* d_ws, size_t ws_size,
                              hipStream_t stream)
{
  (void)in_sizes; (void)n_in; (void)out_size; (void)ws_size;
  const float* x    = (const float*)d_in[0];
  const float* c    = (const float*)d_in[1];
  const float* n1w  = (const float*)d_in[2];
  const float* cw   = (const float*)d_in[3];
  const float* cb   = (const float*)d_in[4];
  const float* qkvw = (const float*)d_in[5];
  const float* qkvb = (const float*)d_in[6];
  const float* qnw  = (const float*)d_in[7];
  const float* knw  = (const float*)d_in[8];
  const float* pw   = (const float*)d_in[9];
  const float* pb   = (const float*)d_in[10];
  const float* ew   = (const float*)d_in[11];
  const float* eb   = (const float*)d_in[12];
  const float* n2w  = (const float*)d_in[13];
  const float* w12w = (const float*)d_in[14];
  const float* w12b = (const float*)d_in[15];
  const float* w3w  = (const float*)d_in[16];
  const float* w3b  = (const float*)d_in[17];
  const float* adaw = (const float*)d_in[18];
  const float* adab = (const float*)d_in[19];
  float* out = (float*)d_out;
  char* ws = (char*)d_ws;
  auto U = [&](size_t off){ return (u16*)(ws + off); };
  auto F = [&](size_t off){ return (float*)(ws + off); };

  // weight conversions (bf16, zero-padded; w12 interleaved for fused swiglu)
  convert_pad<<<dim3(1,1024), 256, 0, stream>>>(cw,   U(OFF_WC),   1024, 1024, 1024);
  convert_pad<<<dim3(1,3072), 256, 0, stream>>>(qkvw, U(OFF_WQKV), 3072, 1024, 1024);
  convert_pad<<<dim3(1,1024), 256, 0, stream>>>(pw,   U(OFF_WPROJ),1024, 1024, 1024);
  convert_pad<<<dim3(1,1024), 256, 0, stream>>>(ew,   U(OFF_WEXP), 1024, 1024, 1024);
  convert_w12i<<<dim3(1,5632), 256, 0, stream>>>(w12w, U(OFF_WW12));
  convert_pad<<<dim3(3,1024), 256, 0, stream>>>(w3w,  U(OFF_WW3),  1024, 2730, 2752);

  ada_kernel<<<1536, 256, 0, stream>>>(c, adaw, adab, F(OFF_ADA));

  // attention branch
  rms_mod<<<4096, 256, 0, stream>>>(x, n1w, F(OFF_ADA), 0, U(OFF_H1));
  gemm_dr<0><<<dim3(8,32), 256, 0, stream>>>(U(OFF_H1), U(OFF_WC), cb, 1024, 1024, 1024, U(OFF_HC), nullptr, nullptr, 0, nullptr);
  gemm_dp2<0><<<dim3(12,32), 256, 0, stream>>>(U(OFF_HC), U(OFF_WQKV), qkvb, 3072, 1024, 3072, U(OFF_QKVO));
  repack_qkv<<<dim3(16,64), 256, 0, stream>>>(U(OFF_QKVO), qnw, knw, U(OFF_Q), U(OFF_K), U(OFF_VT));
  attn_fwd<<<dim3(16,64), 512, 0, stream>>>(U(OFF_Q), U(OFF_K), U(OFF_VT), U(OFF_O));
  gemm_dr<0><<<dim3(8,32), 256, 0, stream>>>(U(OFF_O), U(OFF_WPROJ), pb, 1024, 1024, 1024, U(OFF_PR), nullptr, nullptr, 0, nullptr);
  gemm_dr<1><<<dim3(8,32), 256, 0, stream>>>(U(OFF_PR), U(OFF_WEXP), eb, 1024, 1024, 1024, nullptr, x, F(OFF_ADA), 2, F(OFF_X2));

  // FFN branch (w12 + swiglu fused via interleaved weights)
  rms_mod<<<4096, 256, 0, stream>>>(F(OFF_X2), n2w, F(OFF_ADA), 3, U(OFF_H2));
  gemm_dp2<2><<<dim3(22,32), 256, 0, stream>>>(U(OFF_H2), U(OFF_WW12), w12b, 5632, 1024, 5460, U(OFF_HID));
  gemm_dr<1><<<dim3(8,32), 256, 0, stream>>>(U(OFF_HID), U(OFF_WW3), w3b, 1024, 2752, 1024, nullptr, F(OFF_X2), F(OFF_ADA), 5, out);
}

// Round 11
// 282.306 us; speedup vs baseline: 1.1568x; 1.0836x over previous
//
#include <hip/hip_runtime.h>
#include <hip/hip_bf16.h>
#include <cstdint>
#include <cstddef>

typedef unsigned short u16;
typedef __bf16 bf16x8 __attribute__((ext_vector_type(8)));
typedef __bf16 bf16x4 __attribute__((ext_vector_type(4)));
typedef short   s16x4 __attribute__((ext_vector_type(4)));
typedef float    f32x4 __attribute__((ext_vector_type(4)));
typedef unsigned short u16x2 __attribute__((ext_vector_type(2)));
typedef unsigned short u16x4 __attribute__((ext_vector_type(4)));
typedef unsigned short u16x8 __attribute__((ext_vector_type(8)));

#define DEVI static __device__ __forceinline__

DEVI float b2f(u16 u){ union{unsigned i; float v;} x; x.i=((unsigned)u)<<16; return x.v; }
DEVI u16 f2b(float f){ union{float v; unsigned i;} x; x.v=f; unsigned r=x.i+0x7FFFu+((x.i>>16)&1u); return (u16)(r>>16); }
DEVI f32x4 mfma16(bf16x8 a, bf16x8 b, f32x4 c){ return __builtin_amdgcn_mfma_f32_16x16x32_bf16(a,b,c,0,0,0); }
DEVI f32x4 mfma16k16(bf16x4 a, bf16x4 b, f32x4 c){
#if __has_builtin(__builtin_amdgcn_mfma_f32_16x16x16_bf16)
  return __builtin_amdgcn_mfma_f32_16x16x16_bf16(a,b,c,0,0,0);
#elif __has_builtin(__builtin_amdgcn_mfma_f32_16x16x16bf16_1k)
  return __builtin_amdgcn_mfma_f32_16x16x16bf16_1k((s16x4)a,(s16x4)b,c,0,0,0);
#else
  asm volatile("v_mfma_f32_16x16x16_bf16 %0, %1, %2, %0" : "+v"(c) : "v"(a), "v"(b));
  return c;
#endif
}
DEVI float fexp2(float x){ return __builtin_amdgcn_exp2f(x); }
DEVI void gload16(const void* g, void* l){
  __builtin_amdgcn_global_load_lds((const __attribute__((address_space(1))) void*)g,
                                   (__attribute__((address_space(3))) void*)l, 16, 0, 0);
}
DEVI float silu_f(float x){ return x/(1.f+__expf(-x)); }

// ---------------- workspace layout (bytes) ----------------
static constexpr size_t OFF_WC   = 0;
static constexpr size_t OFF_WQKV = OFF_WC   + (size_t)1024*1024*2;
static constexpr size_t OFF_WPROJ= OFF_WQKV + (size_t)3072*1024*2;
static constexpr size_t OFF_WEXP = OFF_WPROJ+ (size_t)1024*1024*2;
static constexpr size_t OFF_WW12 = OFF_WEXP + (size_t)1024*1024*2;   // pair-interleaved [5632][1024]
static constexpr size_t OFF_WW3  = OFF_WW12 + (size_t)5632*1024*2;
static constexpr size_t OFF_ADA  = OFF_WW3  + (size_t)1024*2752*2;
static constexpr size_t OFF_X2   = OFF_ADA  + (size_t)4*6144*4;
static constexpr size_t OFF_P1   = OFF_X2   + (size_t)4096*1024*4;
static constexpr size_t OFF_H1   = OFF_P1;
static constexpr size_t OFF_HC   = OFF_H1   + (size_t)4096*1024*2;
static constexpr size_t OFF_QKVO = OFF_HC   + (size_t)4096*1024*2;
static constexpr size_t OFF_P2   = OFF_P1   + (size_t)4096*5632*2;
static constexpr size_t OFF_Q    = OFF_P2;
static constexpr size_t OFF_K    = OFF_Q    + (size_t)64*1024*64*2;
static constexpr size_t OFF_VT   = OFF_K    + (size_t)64*1024*64*2;
static constexpr size_t OFF_O    = OFF_VT   + (size_t)64*1024*64*2;
static constexpr size_t OFF_PR   = OFF_O    + (size_t)4096*1024*2;
static constexpr size_t OFF_H2   = OFF_PR   + (size_t)4096*1024*2;
static constexpr size_t OFF_HID  = OFF_P2;                       // [4096][2752] bf16 (reuse: q/k/vt dead)

// ---------------- merged weight conversion (all 1024-col weights in one launch) ----------------
// rows: [0,1024) wc | [1024,4096) qkv | [4096,5120) proj | [5120,6144) exp | [6144,11776) w12 pair-interleaved
__global__ __launch_bounds__(256) void convert_merged(
    const float* __restrict__ cw, const float* __restrict__ qkvw,
    const float* __restrict__ pw, const float* __restrict__ ew,
    const float* __restrict__ w12w, u16* __restrict__ ws16)
{
  int r = blockIdx.x;
  int c0 = threadIdx.x*4;
  const float* src; u16* dst; long srow; bool valid = true;
  if (r < 1024){ src = cw;   dst = ws16 + OFF_WC/2;   srow = r; }
  else if (r < 4096){ src = qkvw; dst = ws16 + OFF_WQKV/2; srow = r-1024; r -= 1024; }
  else if (r < 5120){ src = pw;   dst = ws16 + OFF_WPROJ/2; srow = r-4096; r -= 4096; }
  else if (r < 6144){ src = ew;   dst = ws16 + OFF_WEXP/2; srow = r-5120; r -= 5120; }
  else {
    int rp = r - 6144;                // [0,5632)
    int b16 = rp>>4, w = rp&15;
    int p = b16>>1, half = b16&1;
    int sl = p*16 + w;
    valid = sl < 2730;
    srow = (half ? 2730 : 0) + sl;
    src = w12w; dst = ws16 + OFF_WW12/2; r = rp;
  }
  u16x4 o;
#pragma unroll
  for (int j=0;j<4;j++){
    float f = valid ? src[(size_t)srow*1024 + c0 + j] : 0.f;
    o[j] = f2b(f);
  }
  *(u16x4*)&dst[(size_t)r*1024 + c0] = o;
}

// ---------------- fp32 -> bf16 weight conversion with zero padding (w3 only) ----------------
__global__ __launch_bounds__(256) void convert_pad(const float* __restrict__ src, u16* __restrict__ dst,
                                                   int R, int C, int Cpad)
{
  int r = blockIdx.y;
  int c0 = (blockIdx.x*256 + threadIdx.x)*4;
  if (c0 >= Cpad) return;
  u16x4 o;
#pragma unroll
  for (int j=0;j<4;j++){
    int cc = c0+j;
    float f = (r < R && cc < C) ? src[(size_t)r*C + cc] : 0.f;
    o[j] = f2b(f);
  }
  *(u16x4*)&dst[(size_t)r*Cpad + c0] = o;
}

// ---------------- adaLN: ada = silu(c) @ ada_w.T + ada_b  -> [4][6144] fp32 ----------------
__global__ __launch_bounds__(256) void ada_kernel(const float* __restrict__ c,
    const float* __restrict__ aw, const float* __restrict__ ab, float* __restrict__ ada)
{
  __shared__ float s[4][1024];
  int t = threadIdx.x;
#pragma unroll
  for (int i=0;i<16;i++){
    int idx = i*256 + t;
    float cv = c[idx];
    s[idx>>10][idx&1023] = cv/(1.f+__expf(-cv));
  }
  __syncthreads();
  int wid = t>>6, lane = t&63;
  int j = blockIdx.x*4 + wid;
  const f32x4* wp = (const f32x4*)(aw + (size_t)j*1024);
  float a0=0,a1=0,a2=0,a3=0;
#pragma unroll
  for (int i=0;i<4;i++){
    f32x4 wv = wp[i*64 + lane];
    int k0 = (i*64+lane)*4;
#pragma unroll
    for (int e=0;e<4;e++){
      float w = wv[e];
      a0 += w*s[0][k0+e]; a1 += w*s[1][k0+e]; a2 += w*s[2][k0+e]; a3 += w*s[3][k0+e];
    }
  }
#pragma unroll
  for (int mask=1; mask<64; mask<<=1){
    a0 += __shfl_xor(a0, mask); a1 += __shfl_xor(a1, mask);
    a2 += __shfl_xor(a2, mask); a3 += __shfl_xor(a3, mask);
  }
  if (lane==0){
    float bv = ab[j];
    ada[0*6144 + j] = a0 + bv;
    ada[1*6144 + j] = a1 + bv;
    ada[2*6144 + j] = a2 + bv;
    ada[3*6144 + j] = a3 + bv;
  }
}

// ---------------- fused RMSNorm + modulate -> bf16 ----------------
__global__ __launch_bounds__(256) void rms_mod(const float* __restrict__ x,
    const float* __restrict__ w, const float* __restrict__ ada, int chunkSh,
    u16* __restrict__ out)
{
  int row = blockIdx.x;
  int b = row>>10;
  int t = threadIdx.x;
  int wid = t>>6, lane = t&63;
  f32x4 v = *(const f32x4*)(x + (size_t)row*1024 + t*4);
  float ss = v[0]*v[0]+v[1]*v[1]+v[2]*v[2]+v[3]*v[3];
#pragma unroll
  for (int mask=1; mask<64; mask<<=1) ss += __shfl_xor(ss, mask);
  __shared__ float red[4];
  if (lane==0) red[wid]=ss;
  __syncthreads();
  float rinv = rsqrtf((red[0]+red[1]+red[2]+red[3])*(1.f/1024.f) + 1e-6f);
  int cc = t*4;
  const float* shp = ada + (size_t)b*6144 + (size_t)chunkSh*1024 + cc;
  u16x4 o;
#pragma unroll
  for (int jj=0;jj<4;jj++){
    float val = v[jj]*rinv*w[cc+jj];
    val = val*(1.f+shp[jj+1024]) + shp[jj];
    o[jj] = f2b(val);
  }
  *(u16x4*)&out[(size_t)row*1024 + cc] = o;
}

// ---------------- bf16 GEMM 128x128 (BK=32), ring-6 LDS, depth-5 counted-vmcnt pipeline ----------------
// Grid exactly (8,32): XCD-aware remap so each XCD owns 4 contiguous A-stripes.
template<int EPI>
__global__ __launch_bounds__(256) void gemm_dr(
    const u16* __restrict__ A, const u16* __restrict__ Bw, const float* __restrict__ bias,
    int N, int K, int nbias, u16* __restrict__ outb,
    const float* __restrict__ xres, const float* __restrict__ ada, int adaChunk,
    float* __restrict__ outf)
{
  constexpr int RU = 8192;                 // (128 A-rows + 128 B-rows) * 32 u16
  __shared__ __align__(16) u16 lds[6*RU];  // 96 KB
  int t = threadIdx.x;
  int lane = t&63, w = t>>6;
  int wr = (w>>1)*64, wc = (w&1)*64;
  int lr = lane&15, lg = lane>>4;
  int id = blockIdx.y*8 + blockIdx.x;
  int xcd = id&7, loc = id>>3;
  int bm = xcd*4 + (loc>>3);
  int bn = loc&7;
  int srow = t>>2;
  int schunk = ((t&3) ^ ((t>>3)&3))*8;     // pre-swizzled global source chunk, f(row)=(row>>1)&3
  const u16* pA = A  + (size_t)(bm*128 + srow)*K + schunk;
  const u16* pB = Bw + (size_t)(bn*128 + srow)*K + schunk;
  int rp = (lg ^ ((lr>>1)&3))*8;           // swizzled read position
  int aoff = (wr + lr)*32 + rp;
  int boff = 4096 + (wc + lr)*32 + rp;
  f32x4 acc[4][4] = {};
  int NT = K>>5;

  auto stage = [&](int kt, int slot){
    u16* dst = &lds[slot*RU];
    const u16* sa = pA + (size_t)kt*32;
    const u16* sb = pB + (size_t)kt*32;
    gload16(sa,                dst + t*8);
    gload16(sa + (size_t)64*K, dst + 2048 + t*8);
    gload16(sb,                dst + 4096 + t*8);
    gload16(sb + (size_t)64*K, dst + 6144 + t*8);
  };
  auto compute = [&](int slot){
    const u16* lb = &lds[slot*RU];
    bf16x8 af[4], bfr[4];
#pragma unroll
    for (int m=0;m<4;m++) af[m]  = *(const bf16x8*)&lb[aoff + m*512];
#pragma unroll
    for (int n=0;n<4;n++) bfr[n] = *(const bf16x8*)&lb[boff + n*512];
    __builtin_amdgcn_s_setprio(1);
#pragma unroll
    for (int m=0;m<4;m++)
#pragma unroll
      for (int n=0;n<4;n++)
        acc[m][n] = mfma16(af[m], bfr[n], acc[m][n]);
    __builtin_amdgcn_s_setprio(0);
  };

#pragma unroll
  for (int i=0;i<5;i++) stage(i, i);
  asm volatile("s_waitcnt vmcnt(16)" ::: "memory");
  __builtin_amdgcn_s_barrier();
  __builtin_amdgcn_sched_barrier(0);

  int cur = 0, stg = 5;
  for (int kt=0; kt<NT-5; ++kt){
    stage(kt+5, stg);
    compute(cur);
    asm volatile("s_waitcnt vmcnt(16)" ::: "memory");
    __builtin_amdgcn_s_barrier();
    __builtin_amdgcn_sched_barrier(0);
    cur = (cur==5)?0:cur+1;
    stg = (stg==5)?0:stg+1;
  }
  compute(cur); cur=(cur==5)?0:cur+1;
  asm volatile("s_waitcnt vmcnt(12)" ::: "memory");
  __builtin_amdgcn_s_barrier(); __builtin_amdgcn_sched_barrier(0);
  compute(cur); cur=(cur==5)?0:cur+1;
  asm volatile("s_waitcnt vmcnt(8)" ::: "memory");
  __builtin_amdgcn_s_barrier(); __builtin_amdgcn_sched_barrier(0);
  compute(cur); cur=(cur==5)?0:cur+1;
  asm volatile("s_waitcnt vmcnt(4)" ::: "memory");
  __builtin_amdgcn_s_barrier(); __builtin_amdgcn_sched_barrier(0);
  compute(cur); cur=(cur==5)?0:cur+1;
  asm volatile("s_waitcnt vmcnt(0)" ::: "memory");
  __builtin_amdgcn_s_barrier(); __builtin_amdgcn_sched_barrier(0);
  compute(cur);

#pragma unroll
  for (int n=0;n<4;n++){
    int col = bn*128 + wc + n*16 + lr;
    float bv = (col < nbias) ? bias[col] : 0.f;
#pragma unroll
    for (int m=0;m<4;m++){
      int row0 = bm*128 + wr + m*16 + lg*4;
#pragma unroll
      for (int r=0;r<4;r++){
        int row = row0 + r;
        float v = acc[m][n][r] + bv;
        if constexpr (EPI==0){
          outb[(size_t)row*N + col] = f2b(v);
        } else {
          int bb = row>>10;
          float g = ada[(size_t)bb*6144 + (size_t)adaChunk*1024 + col];
          outf[(size_t)row*1024 + col] = xres[(size_t)row*1024 + col] + g*v;
        }
      }
    }
  }
}

// ---------------- bf16 GEMM 128x256 (BK=32), 4 waves, ring-3, counted vmcnt ----------------
// EPI 0: bf16 out ld=N. EPI 2: fused SwiGLU, pair-interleaved B (x1 at even nf, x2 at odd nf) -> hid ld=2752.
template<int EPI>
__global__ __launch_bounds__(256,2) void gemm_dp2(
    const u16* __restrict__ A, const u16* __restrict__ Bw, const float* __restrict__ bias,
    int N, int K, int nbias, u16* __restrict__ outb)
{
  constexpr int AU = 128*32;          // 4096 u16
  constexpr int RU = AU + 256*32;     // 12288 u16 = 24KB
  __shared__ __align__(16) u16 lds[3*RU];
  int t = threadIdx.x;
  int lane = t&63, w = t>>6;
  int wr = w>>1, wc = w&1;            // 2x2 wave grid, wave tile 64x128
  int lr = lane&15, lg = lane>>4;
  int bm = blockIdx.y, bn = blockIdx.x;
  int schunk = ((t&3) ^ ((t>>3)&3))*8;
  const u16* pA = A  + (size_t)(bm*128 + (t>>2))*K + schunk;
  const u16* pB = Bw + (size_t)(bn*256 + (t>>2))*K + schunk;
  int rsw  = (lg ^ ((lr>>1)&3))*8;
  int aoff = (wr*64 + lr)*32 + rsw;
  int boff = AU + (wc*128 + lr)*32 + rsw;
  f32x4 acc[4][8] = {};
  int NT = K>>5;

  auto stage = [&](int kt, int rg){
    u16* dst = &lds[rg*RU];
    const u16* sa = pA + (size_t)kt*32;
    const u16* sb = pB + (size_t)kt*32;
    gload16(sa,                  dst + t*8);
    gload16(sa + (size_t)64*K,   dst + 2048 + t*8);
#pragma unroll
    for (int i=0;i<4;i++)
      gload16(sb + (size_t)(i*64)*K, dst + AU + i*2048 + t*8);
  };

  stage(0, 0);
  stage(1, 1);
  asm volatile("s_waitcnt vmcnt(6)" ::: "memory");
  __builtin_amdgcn_s_barrier();
  __builtin_amdgcn_sched_barrier(0);

  int cur = 0, stg = 2;
  for (int kt=0; kt<NT; ++kt){
    const u16* lb = &lds[cur*RU];
    if (kt+2 < NT) stage(kt+2, stg);
    bf16x8 af[4], bfr[8];
#pragma unroll
    for (int mf=0;mf<4;mf++) af[mf] = *(const bf16x8*)&lb[aoff + mf*512];
#pragma unroll
    for (int nf=0;nf<8;nf++) bfr[nf] = *(const bf16x8*)&lb[boff + nf*512];
    __builtin_amdgcn_s_setprio(1);
#pragma unroll
    for (int mf=0;mf<4;mf++)
#pragma unroll
      for (int nf=0;nf<8;nf++)
        acc[mf][nf] = mfma16(af[mf], bfr[nf], acc[mf][nf]);
    __builtin_amdgcn_s_setprio(0);
    if (kt+2 < NT){
      asm volatile("s_waitcnt vmcnt(6)" ::: "memory");
    } else if (kt+1 < NT){
      asm volatile("s_waitcnt vmcnt(0)" ::: "memory");
    }
    if (kt+1 < NT){
      __builtin_amdgcn_s_barrier();
      __builtin_amdgcn_sched_barrier(0);
    }
    cur = (cur==2)?0:cur+1;
    stg = (stg==2)?0:stg+1;
  }
  if constexpr (EPI==0){
#pragma unroll
    for (int nf=0;nf<8;nf++){
      int col = bn*256 + wc*128 + nf*16 + lr;
      float bv = (col < nbias) ? bias[col] : 0.f;
#pragma unroll
      for (int mf=0; mf<4; mf++){
        int row0 = bm*128 + wr*64 + mf*16 + lg*4;
#pragma unroll
        for (int r=0;r<4;r++)
          outb[(size_t)(row0+r)*N + col] = f2b(acc[mf][nf][r] + bv);
      }
    }
  } else {
    // fused SwiGLU, pair-interleaved: even nf = x1, odd nf = x2, same lane, pair col P = p*16+lr.
#pragma unroll
    for (int nf=0;nf<8;nf+=2){
      int p = bn*8 + wc*4 + (nf>>1);
      int P = p*16 + lr;
      bool vP = (P < 2730);
      float b1 = vP ? bias[P] : 0.f;
      float b2 = vP ? bias[2730+P] : 0.f;
#pragma unroll
      for (int mf=0; mf<4; mf++){
        int row0 = bm*128 + wr*64 + mf*16 + lg*4;
#pragma unroll
        for (int r=0;r<4;r++){
          float x1 = acc[mf][nf][r] + b1;
          float x2 = acc[mf][nf+1][r] + b2;
          if (vP) outb[(size_t)(row0+r)*2752 + P] = f2b(silu_f(x1)*x2);
        }
      }
    }
  }
}

// ---------------- qkv repack: rms-norm q,k per head, fragment-major K/V for attention ----------------
__global__ __launch_bounds__(256) void repack_qkv(const u16* __restrict__ qkvO,
    const float* __restrict__ qnw, const float* __restrict__ knw,
    u16* __restrict__ qO, u16* __restrict__ kO, u16* __restrict__ vO)
{
  __shared__ u16 ldsv[64][64];
  int bh = blockIdx.y, b = bh>>4, h = bh&15;
  int n0 = blockIdx.x*64;
  int t = threadIdx.x;
  int nr = t>>2, qd = (t&3)*16;
  const u16* rowp = qkvO + (size_t)(b*1024 + n0 + nr)*3072;
  // Q: rms-norm * qn_w * (1/8)*log2e
  {
    u16x8 a0 = *(const u16x8*)(rowp + h*64 + qd);
    u16x8 a1 = *(const u16x8*)(rowp + h*64 + qd + 8);
    float f[16]; float ss=0;
#pragma unroll
    for (int jj=0;jj<8;jj++){ f[jj]=b2f(a0[jj]); f[8+jj]=b2f(a1[jj]); }
#pragma unroll
    for (int jj=0;jj<16;jj++) ss += f[jj]*f[jj];
    ss += __shfl_xor(ss,1); ss += __shfl_xor(ss,2);
    float rinv = rsqrtf(ss*(1.f/64.f)+1e-6f)*0.125f*1.44269504089f;
    u16x8 o0,o1;
#pragma unroll
    for (int jj=0;jj<8;jj++){ o0[jj]=f2b(f[jj]*rinv*qnw[qd+jj]); o1[jj]=f2b(f[8+jj]*rinv*qnw[qd+8+jj]); }
    u16* dst = qO + ((size_t)bh*1024 + n0 + nr)*64 + qd;
    *(u16x8*)dst = o0; *(u16x8*)(dst+8) = o1;
  }
  // K: rms-norm * kn_w -> fragment-major
  {
    u16x8 a0 = *(const u16x8*)(rowp + 1024 + h*64 + qd);
    u16x8 a1 = *(const u16x8*)(rowp + 1024 + h*64 + qd + 8);
    float f[16]; float ss=0;
#pragma unroll
    for (int jj=0;jj<8;jj++){ f[jj]=b2f(a0[jj]); f[8+jj]=b2f(a1[jj]); }
#pragma unroll
    for (int jj=0;jj<16;jj++) ss += f[jj]*f[jj];
    ss += __shfl_xor(ss,1); ss += __shfl_xor(ss,2);
    float rinv = rsqrtf(ss*(1.f/64.f)+1e-6f);
    u16x8 o0,o1;
#pragma unroll
    for (int jj=0;jj<8;jj++){ o0[jj]=f2b(f[jj]*rinv*knw[qd+jj]); o1[jj]=f2b(f[8+jj]*rinv*knw[qd+8+jj]); }
    int t16 = (n0 + nr)>>4, lrk = nr&15;
    {
      int d0 = qd, c = d0>>5, lg = (d0>>3)&3;
      *(u16x8*)(kO + (size_t)bh*65536 + ((size_t)(t16*2+c)*64 + lg*16 + lrk)*8) = o0;
    }
    {
      int d0 = qd+8, c = d0>>5, lg = (d0>>3)&3;
      *(u16x8*)(kO + (size_t)bh*65536 + ((size_t)(t16*2+c)*64 + lg*16 + lrk)*8) = o1;
    }
  }
  // V: transpose via LDS, then write fragment-major
  {
    u16x8 a0 = *(const u16x8*)(rowp + 2048 + h*64 + qd);
    u16x8 a1 = *(const u16x8*)(rowp + 2048 + h*64 + qd + 8);
#pragma unroll
    for (int jj=0;jj<8;jj++){ ldsv[qd+jj][nr] = a0[jj]; ldsv[qd+8+jj][nr] = a1[jj]; }
  }
  __syncthreads();
  {
    int d = t>>2, ns = (t&3)*16;
    int tt = d>>4, lrv = d&15;
    int m = (n0 + ns)>>5;
    int hf = (ns>>4)&1;
    u16* basep = vO + (size_t)bh*65536 + ((size_t)(m*4+tt)*64 + lrv)*8 + hf*4;
#pragma unroll
    for (int g=0; g<4; ++g){
      u16x4 wv4 = { ldsv[d][ns+g*4], ldsv[d][ns+g*4+1], ldsv[d][ns+g*4+2], ldsv[d][ns+g*4+3] };
      *(u16x4*)(basep + (size_t)g*128) = wv4;
    }
  }
}

// ---------------- flash attention: split-K x2, coalesced fragment loads, defer-max, exp2 ----------------
__global__ __launch_bounds__(512) void attn_fwd(const u16* __restrict__ qO,
    const u16* __restrict__ kO, const u16* __restrict__ vO, u16* __restrict__ o)
{
  __shared__ __align__(16) float obuf[4][64][16];
  __shared__ __align__(16) float mlb[4][2][2][16];
  int bh = blockIdx.y, b = bh>>4, h = bh&15;
  int w = threadIdx.x>>6, lane = threadIdx.x&63;
  int pair = w>>1, half = w&1;
  int lr = lane&15, lg = lane>>4;
  int q0 = blockIdx.x*64 + pair*16;
  const u16* qp = qO + ((size_t)bh*1024 + q0 + lr)*64 + lg*8;
  bf16x8 qf0 = *(const bf16x8*)qp;
  bf16x8 qf1 = *(const bf16x8*)(qp + 32);
  const u16* kb = kO + (size_t)bh*65536 + (size_t)half*32768 + (size_t)lane*8;
  const u16* vb = vO + (size_t)bh*65536 + (size_t)half*32768 + (size_t)lane*8;
  f32x4 oacc[4] = {};
  float mrun = -3.0e38f, lrun = 0.f;
  for (int it=0; it<16; ++it){
    const u16* kp = kb + (size_t)it*4096;
    bf16x8 k00 = *(const bf16x8*)(kp);
    bf16x8 k01 = *(const bf16x8*)(kp + 512);
    bf16x8 k10 = *(const bf16x8*)(kp + 1024);
    bf16x8 k11 = *(const bf16x8*)(kp + 1536);
    f32x4 s0 = {}, s1 = {};
    s0 = mfma16(k00, qf0, s0); s0 = mfma16(k01, qf1, s0);
    s1 = mfma16(k10, qf0, s1); s1 = mfma16(k11, qf1, s1);
    const u16* vp = vb + (size_t)it*2048;
    bf16x8 vv[4];
#pragma unroll
    for (int tt=0;tt<4;tt++) vv[tt] = *(const bf16x8*)(vp + tt*512);
    float pm = fmaxf(fmaxf(fmaxf(s0[0],s0[1]),fmaxf(s0[2],s0[3])),
                     fmaxf(fmaxf(s1[0],s1[1]),fmaxf(s1[2],s1[3])));
    pm = fmaxf(pm, __shfl_xor(pm, 16));
    pm = fmaxf(pm, __shfl_xor(pm, 32));
    if (__any(pm > mrun + 8.f)){
      float mnew = fmaxf(mrun, pm);
      float alpha = fexp2(mrun - mnew);
      mrun = mnew;
      lrun *= alpha;
      float ar[4];
#pragma unroll
      for (int r=0;r<4;r++) ar[r] = __shfl(alpha, lg*4 + r);
#pragma unroll
      for (int tt=0;tt<4;tt++)
#pragma unroll
        for (int r=0;r<4;r++) oacc[tt][r] *= ar[r];
    }
    float p0[4], p1[4]; float ls = 0.f;
#pragma unroll
    for (int r=0;r<4;r++){ p0[r]=fexp2(s0[r]-mrun); p1[r]=fexp2(s1[r]-mrun); ls += p0[r]+p1[r]; }
    ls += __shfl_xor(ls, 16); ls += __shfl_xor(ls, 32);
    lrun += ls;
    bf16x4 pa0, pa1;
#pragma unroll
    for (int r=0;r<4;r++){ pa0[r] = (__bf16)p0[r]; pa1[r] = (__bf16)p1[r]; }
#pragma unroll
    for (int tt=0;tt<4;tt++){
      bf16x4* vh = (bf16x4*)&vv[tt];
      oacc[tt] = mfma16k16(pa0, vh[0], oacc[tt]);
      oacc[tt] = mfma16k16(pa1, vh[1], oacc[tt]);
    }
  }
  if (lg==0){ mlb[pair][half][0][lr] = mrun; mlb[pair][half][1][lr] = lrun; }
  __syncthreads();
  f32x4 m0 = *(const f32x4*)&mlb[pair][0][0][lg*4];
  f32x4 l0 = *(const f32x4*)&mlb[pair][0][1][lg*4];
  f32x4 m1 = *(const f32x4*)&mlb[pair][1][0][lg*4];
  f32x4 l1 = *(const f32x4*)&mlb[pair][1][1][lg*4];
  f32x4 fh;
#pragma unroll
  for (int r=0;r<4;r++){
    float m = fmaxf(m0[r], m1[r]);
    float e0 = fexp2(m0[r]-m), e1 = fexp2(m1[r]-m);
    float li = 1.f/(l0[r]*e0 + l1[r]*e1);
    fh[r] = (half ? e1 : e0)*li;
  }
  if (half==1){
#pragma unroll
    for (int tt=0;tt<4;tt++){
      f32x4 tv;
#pragma unroll
      for (int r=0;r<4;r++) tv[r] = oacc[tt][r]*fh[r];
      *(f32x4*)&obuf[pair][lane][tt*4] = tv;
    }
  }
  __syncthreads();
  if (half==0){
#pragma unroll
    for (int tt=0;tt<4;tt++){
      f32x4 p = *(const f32x4*)&obuf[pair][lane][tt*4];
#pragma unroll
      for (int r=0;r<4;r++){
        int row = (b<<10) + q0 + lg*4 + r;
        int col = h*64 + tt*16 + lr;
        o[(size_t)row*1024 + col] = f2b(oacc[tt][r]*fh[r] + p[r]);
      }
    }
  }
}

extern "C" void kernel_launch(void* const* d_in, const int* in_sizes, int n_in,
                              void* d_out, int out_size, void* d_ws, size_t ws_size,
                              hipStream_t stream)
{
  (void)in_sizes; (void)n_in; (void)out_size; (void)ws_size;
  const float* x    = (const float*)d_in[0];
  const float* c    = (const float*)d_in[1];
  const float* n1w  = (const float*)d_in[2];
  const float* cw   = (const float*)d_in[3];
  const float* cb   = (const float*)d_in[4];
  const float* qkvw = (const float*)d_in[5];
  const float* qkvb = (const float*)d_in[6];
  const float* qnw  = (const float*)d_in[7];
  const float* knw  = (const float*)d_in[8];
  const float* pw   = (const float*)d_in[9];
  const float* pb   = (const float*)d_in[10];
  const float* ew   = (const float*)d_in[11];
  const float* eb   = (const float*)d_in[12];
  const float* n2w  = (const float*)d_in[13];
  const float* w12w = (const float*)d_in[14];
  const float* w12b = (const float*)d_in[15];
  const float* w3w  = (const float*)d_in[16];
  const float* w3b  = (const float*)d_in[17];
  const float* adaw = (const float*)d_in[18];
  const float* adab = (const float*)d_in[19];
  float* out = (float*)d_out;
  char* ws = (char*)d_ws;
  auto U = [&](size_t off){ return (u16*)(ws + off); };
  auto F = [&](size_t off){ return (float*)(ws + off); };

  // weight conversions: merged (wc/qkv/proj/exp/w12-interleaved) + w3
  convert_merged<<<11776, 256, 0, stream>>>(cw, qkvw, pw, ew, w12w, (u16*)ws);
  convert_pad<<<dim3(3,1024), 256, 0, stream>>>(w3w, U(OFF_WW3), 1024, 2730, 2752);

  ada_kernel<<<1536, 256, 0, stream>>>(c, adaw, adab, F(OFF_ADA));

  // attention branch
  rms_mod<<<4096, 256, 0, stream>>>(x, n1w, F(OFF_ADA), 0, U(OFF_H1));
  gemm_dr<0><<<dim3(8,32), 256, 0, stream>>>(U(OFF_H1), U(OFF_WC), cb, 1024, 1024, 1024, U(OFF_HC), nullptr, nullptr, 0, nullptr);
  gemm_dp2<0><<<dim3(12,32), 256, 0, stream>>>(U(OFF_HC), U(OFF_WQKV), qkvb, 3072, 1024, 3072, U(OFF_QKVO));
  repack_qkv<<<dim3(16,64), 256, 0, stream>>>(U(OFF_QKVO), qnw, knw, U(OFF_Q), U(OFF_K), U(OFF_VT));
  attn_fwd<<<dim3(16,64), 512, 0, stream>>>(U(OFF_Q), U(OFF_K), U(OFF_VT), U(OFF_O));
  gemm_dr<0><<<dim3(8,32), 256, 0, stream>>>(U(OFF_O), U(OFF_WPROJ), pb, 1024, 1024, 1024, U(OFF_PR), nullptr, nullptr, 0, nullptr);
  gemm_dr<1><<<dim3(8,32), 256, 0, stream>>>(U(OFF_PR), U(OFF_WEXP), eb, 1024, 1024, 1024, nullptr, x, F(OFF_ADA), 2, F(OFF_X2));

  // FFN branch (w12 + swiglu fused via pair-interleaved weights)
  rms_mod<<<4096, 256, 0, stream>>>(F(OFF_X2), n2w, F(OFF_ADA), 3, U(OFF_H2));
  gemm_dp2<2><<<dim3(22,32), 256, 0, stream>>>(U(OFF_H2), U(OFF_WW12), w12b, 5632, 1024, 5460, U(OFF_HID));
  gemm_dr<1><<<dim3(8,32), 256, 0, stream>>>(U(OFF_HID), U(OFF_WW3), w3b, 1024, 2752, 1024, nullptr, F(OFF_X2), F(OFF_ADA), 5, out);
}

// Round 12
// 277.509 us; speedup vs baseline: 1.1768x; 1.0173x over previous
//
#include <hip/hip_runtime.h>
#include <hip/hip_bf16.h>
#include <cstdint>
#include <cstddef>

typedef unsigned short u16;
typedef __bf16 bf16x8 __attribute__((ext_vector_type(8)));
typedef __bf16 bf16x4 __attribute__((ext_vector_type(4)));
typedef short   s16x4 __attribute__((ext_vector_type(4)));
typedef float    f32x4 __attribute__((ext_vector_type(4)));
typedef unsigned short u16x2 __attribute__((ext_vector_type(2)));
typedef unsigned short u16x4 __attribute__((ext_vector_type(4)));
typedef unsigned short u16x8 __attribute__((ext_vector_type(8)));

#define DEVI static __device__ __forceinline__

DEVI float b2f(u16 u){ union{unsigned i; float v;} x; x.i=((unsigned)u)<<16; return x.v; }
DEVI u16 f2b(float f){ union{float v; unsigned i;} x; x.v=f; unsigned r=x.i+0x7FFFu+((x.i>>16)&1u); return (u16)(r>>16); }
DEVI f32x4 mfma16(bf16x8 a, bf16x8 b, f32x4 c){ return __builtin_amdgcn_mfma_f32_16x16x32_bf16(a,b,c,0,0,0); }
DEVI f32x4 mfma16k16(bf16x4 a, bf16x4 b, f32x4 c){
#if __has_builtin(__builtin_amdgcn_mfma_f32_16x16x16_bf16)
  return __builtin_amdgcn_mfma_f32_16x16x16_bf16(a,b,c,0,0,0);
#elif __has_builtin(__builtin_amdgcn_mfma_f32_16x16x16bf16_1k)
  return __builtin_amdgcn_mfma_f32_16x16x16bf16_1k((s16x4)a,(s16x4)b,c,0,0,0);
#else
  asm volatile("v_mfma_f32_16x16x16_bf16 %0, %1, %2, %0" : "+v"(c) : "v"(a), "v"(b));
  return c;
#endif
}
DEVI float fexp2(float x){ return __builtin_amdgcn_exp2f(x); }
DEVI void gload16(const void* g, void* l){
  __builtin_amdgcn_global_load_lds((const __attribute__((address_space(1))) void*)g,
                                   (__attribute__((address_space(3))) void*)l, 16, 0, 0);
}
DEVI float silu_f(float x){ return x/(1.f+__expf(-x)); }

// ---------------- workspace layout (bytes) ----------------
static constexpr size_t OFF_WC   = 0;
static constexpr size_t OFF_WQKV = OFF_WC   + (size_t)1024*1024*2;
static constexpr size_t OFF_WPROJ= OFF_WQKV + (size_t)3072*1024*2;
static constexpr size_t OFF_WEXP = OFF_WPROJ+ (size_t)1024*1024*2;
static constexpr size_t OFF_WW12 = OFF_WEXP + (size_t)1024*1024*2;   // pair-interleaved [5632][1024]
static constexpr size_t OFF_WW3  = OFF_WW12 + (size_t)5632*1024*2;
static constexpr size_t OFF_ADA  = OFF_WW3  + (size_t)1024*2752*2;
static constexpr size_t OFF_X2   = OFF_ADA  + (size_t)4*6144*4;
static constexpr size_t OFF_P1   = OFF_X2   + (size_t)4096*1024*4;
static constexpr size_t OFF_H1   = OFF_P1;
static constexpr size_t OFF_HC   = OFF_H1   + (size_t)4096*1024*2;
static constexpr size_t OFF_QKVO = OFF_HC   + (size_t)4096*1024*2;
static constexpr size_t OFF_P2   = OFF_P1   + (size_t)4096*5632*2;
static constexpr size_t OFF_Q    = OFF_P2;
static constexpr size_t OFF_K    = OFF_Q    + (size_t)64*1024*64*2;
static constexpr size_t OFF_VT   = OFF_K    + (size_t)64*1024*64*2;
static constexpr size_t OFF_O    = OFF_VT   + (size_t)64*1024*64*2;
static constexpr size_t OFF_PR   = OFF_O    + (size_t)4096*1024*2;
static constexpr size_t OFF_H2   = OFF_PR   + (size_t)4096*1024*2;
static constexpr size_t OFF_HID  = OFF_P2;                       // [4096][2752] bf16 (reuse: q/k/vt dead)

// ---------------- merged weight conversion (all 1024-col weights in one launch) ----------------
// rows: [0,1024) wc | [1024,4096) qkv | [4096,5120) proj | [5120,6144) exp | [6144,11776) w12 pair-interleaved
__global__ __launch_bounds__(256) void convert_merged(
    const float* __restrict__ cw, const float* __restrict__ qkvw,
    const float* __restrict__ pw, const float* __restrict__ ew,
    const float* __restrict__ w12w, u16* __restrict__ ws16)
{
  int r = blockIdx.x;
  int c0 = threadIdx.x*4;
  const float* src; u16* dst; long srow; bool valid = true;
  if (r < 1024){ src = cw;   dst = ws16 + OFF_WC/2;   srow = r; }
  else if (r < 4096){ src = qkvw; dst = ws16 + OFF_WQKV/2; srow = r-1024; r -= 1024; }
  else if (r < 5120){ src = pw;   dst = ws16 + OFF_WPROJ/2; srow = r-4096; r -= 4096; }
  else if (r < 6144){ src = ew;   dst = ws16 + OFF_WEXP/2; srow = r-5120; r -= 5120; }
  else {
    int rp = r - 6144;                // [0,5632)
    int b16 = rp>>4, w = rp&15;
    int p = b16>>1, half = b16&1;
    int sl = p*16 + w;
    valid = sl < 2730;
    srow = (half ? 2730 : 0) + sl;
    src = w12w; dst = ws16 + OFF_WW12/2; r = rp;
  }
  u16x4 o;
#pragma unroll
  for (int j=0;j<4;j++){
    float f = valid ? src[(size_t)srow*1024 + c0 + j] : 0.f;
    o[j] = f2b(f);
  }
  *(u16x4*)&dst[(size_t)r*1024 + c0] = o;
}

// ---------------- fp32 -> bf16 weight conversion with zero padding (w3 only) ----------------
__global__ __launch_bounds__(256) void convert_pad(const float* __restrict__ src, u16* __restrict__ dst,
                                                   int R, int C, int Cpad)
{
  int r = blockIdx.y;
  int c0 = (blockIdx.x*256 + threadIdx.x)*4;
  if (c0 >= Cpad) return;
  u16x4 o;
#pragma unroll
  for (int j=0;j<4;j++){
    int cc = c0+j;
    float f = (r < R && cc < C) ? src[(size_t)r*C + cc] : 0.f;
    o[j] = f2b(f);
  }
  *(u16x4*)&dst[(size_t)r*Cpad + c0] = o;
}

// ---------------- adaLN: ada = silu(c) @ ada_w.T + ada_b  -> [4][6144] fp32 ----------------
__global__ __launch_bounds__(256) void ada_kernel(const float* __restrict__ c,
    const float* __restrict__ aw, const float* __restrict__ ab, float* __restrict__ ada)
{
  __shared__ float s[4][1024];
  int t = threadIdx.x;
#pragma unroll
  for (int i=0;i<16;i++){
    int idx = i*256 + t;
    float cv = c[idx];
    s[idx>>10][idx&1023] = cv/(1.f+__expf(-cv));
  }
  __syncthreads();
  int wid = t>>6, lane = t&63;
  int j = blockIdx.x*4 + wid;
  const f32x4* wp = (const f32x4*)(aw + (size_t)j*1024);
  float a0=0,a1=0,a2=0,a3=0;
#pragma unroll
  for (int i=0;i<4;i++){
    f32x4 wv = wp[i*64 + lane];
    int k0 = (i*64+lane)*4;
#pragma unroll
    for (int e=0;e<4;e++){
      float w = wv[e];
      a0 += w*s[0][k0+e]; a1 += w*s[1][k0+e]; a2 += w*s[2][k0+e]; a3 += w*s[3][k0+e];
    }
  }
#pragma unroll
  for (int mask=1; mask<64; mask<<=1){
    a0 += __shfl_xor(a0, mask); a1 += __shfl_xor(a1, mask);
    a2 += __shfl_xor(a2, mask); a3 += __shfl_xor(a3, mask);
  }
  if (lane==0){
    float bv = ab[j];
    ada[0*6144 + j] = a0 + bv;
    ada[1*6144 + j] = a1 + bv;
    ada[2*6144 + j] = a2 + bv;
    ada[3*6144 + j] = a3 + bv;
  }
}

// ---------------- fused RMSNorm + modulate -> bf16 ----------------
__global__ __launch_bounds__(256) void rms_mod(const float* __restrict__ x,
    const float* __restrict__ w, const float* __restrict__ ada, int chunkSh,
    u16* __restrict__ out)
{
  int row = blockIdx.x;
  int b = row>>10;
  int t = threadIdx.x;
  int wid = t>>6, lane = t&63;
  f32x4 v = *(const f32x4*)(x + (size_t)row*1024 + t*4);
  float ss = v[0]*v[0]+v[1]*v[1]+v[2]*v[2]+v[3]*v[3];
#pragma unroll
  for (int mask=1; mask<64; mask<<=1) ss += __shfl_xor(ss, mask);
  __shared__ float red[4];
  if (lane==0) red[wid]=ss;
  __syncthreads();
  float rinv = rsqrtf((red[0]+red[1]+red[2]+red[3])*(1.f/1024.f) + 1e-6f);
  int cc = t*4;
  const float* shp = ada + (size_t)b*6144 + (size_t)chunkSh*1024 + cc;
  u16x4 o;
#pragma unroll
  for (int jj=0;jj<4;jj++){
    float val = v[jj]*rinv*w[cc+jj];
    val = val*(1.f+shp[jj+1024]) + shp[jj];
    o[jj] = f2b(val);
  }
  *(u16x4*)&out[(size_t)row*1024 + cc] = o;
}

// ---------------- bf16 GEMM 128x128 (BK=32), ring-4 LDS (64KB, 2 blocks/CU), depth-3 pipeline ----------------
// Grid exactly (8,32): XCD-aware remap so each XCD owns 4 contiguous A-stripes.
template<int EPI>
__global__ __launch_bounds__(256) void gemm_dr(
    const u16* __restrict__ A, const u16* __restrict__ Bw, const float* __restrict__ bias,
    int N, int K, int nbias, u16* __restrict__ outb,
    const float* __restrict__ xres, const float* __restrict__ ada, int adaChunk,
    float* __restrict__ outf)
{
  constexpr int RU = 8192;                 // (128 A-rows + 128 B-rows) * 32 u16
  __shared__ __align__(16) u16 lds[4*RU];  // 64 KB -> 2 blocks/CU
  int t = threadIdx.x;
  int lane = t&63, w = t>>6;
  int wr = (w>>1)*64, wc = (w&1)*64;
  int lr = lane&15, lg = lane>>4;
  int id = blockIdx.y*8 + blockIdx.x;
  int xcd = id&7, loc = id>>3;
  int bm = xcd*4 + (loc>>3);
  int bn = loc&7;
  int srow = t>>2;
  int schunk = ((t&3) ^ ((t>>3)&3))*8;     // pre-swizzled global source chunk, f(row)=(row>>1)&3
  const u16* pA = A  + (size_t)(bm*128 + srow)*K + schunk;
  const u16* pB = Bw + (size_t)(bn*128 + srow)*K + schunk;
  int rp = (lg ^ ((lr>>1)&3))*8;           // swizzled read position
  int aoff = (wr + lr)*32 + rp;
  int boff = 4096 + (wc + lr)*32 + rp;
  f32x4 acc[4][4] = {};
  int NT = K>>5;

  auto stage = [&](int kt, int slot){
    u16* dst = &lds[slot*RU];
    const u16* sa = pA + (size_t)kt*32;
    const u16* sb = pB + (size_t)kt*32;
    gload16(sa,                dst + t*8);
    gload16(sa + (size_t)64*K, dst + 2048 + t*8);
    gload16(sb,                dst + 4096 + t*8);
    gload16(sb + (size_t)64*K, dst + 6144 + t*8);
  };
  auto compute = [&](int slot){
    const u16* lb = &lds[slot*RU];
    bf16x8 af[4], bfr[4];
#pragma unroll
    for (int m=0;m<4;m++) af[m]  = *(const bf16x8*)&lb[aoff + m*512];
#pragma unroll
    for (int n=0;n<4;n++) bfr[n] = *(const bf16x8*)&lb[boff + n*512];
    __builtin_amdgcn_s_setprio(1);
#pragma unroll
    for (int m=0;m<4;m++)
#pragma unroll
      for (int n=0;n<4;n++)
        acc[m][n] = mfma16(af[m], bfr[n], acc[m][n]);
    __builtin_amdgcn_s_setprio(0);
  };

  // prologue: stage tiles 0..2 into slots 0..2 (12 loads in flight)
#pragma unroll
  for (int i=0;i<3;i++) stage(i, i);
  asm volatile("s_waitcnt vmcnt(8)" ::: "memory");    // tile 0 ready
  __builtin_amdgcn_s_barrier();
  __builtin_amdgcn_sched_barrier(0);

  int cur = 0, stg = 3;
  for (int kt=0; kt<NT-3; ++kt){
    stage(kt+3, stg);
    compute(cur);
    asm volatile("s_waitcnt vmcnt(8)" ::: "memory");  // next tile ready, 8 stay in flight
    __builtin_amdgcn_s_barrier();
    __builtin_amdgcn_sched_barrier(0);
    cur = (cur==3)?0:cur+1;
    stg = (stg==3)?0:stg+1;
  }
  // tail: 3 tiles, drain 8 -> 4 -> 0
  compute(cur); cur=(cur==3)?0:cur+1;
  asm volatile("s_waitcnt vmcnt(4)" ::: "memory");
  __builtin_amdgcn_s_barrier(); __builtin_amdgcn_sched_barrier(0);
  compute(cur); cur=(cur==3)?0:cur+1;
  asm volatile("s_waitcnt vmcnt(0)" ::: "memory");
  __builtin_amdgcn_s_barrier(); __builtin_amdgcn_sched_barrier(0);
  compute(cur);

#pragma unroll
  for (int n=0;n<4;n++){
    int col = bn*128 + wc + n*16 + lr;
    float bv = (col < nbias) ? bias[col] : 0.f;
#pragma unroll
    for (int m=0;m<4;m++){
      int row0 = bm*128 + wr + m*16 + lg*4;
#pragma unroll
      for (int r=0;r<4;r++){
        int row = row0 + r;
        float v = acc[m][n][r] + bv;
        if constexpr (EPI==0){
          outb[(size_t)row*N + col] = f2b(v);
        } else {
          int bb = row>>10;
          float g = ada[(size_t)bb*6144 + (size_t)adaChunk*1024 + col];
          outf[(size_t)row*1024 + col] = xres[(size_t)row*1024 + col] + g*v;
        }
      }
    }
  }
}

// ---------------- bf16 GEMM 128x256 (BK=32), 4 waves, ring-3, counted vmcnt, XCD chunk remap ----------------
// EPI 0: bf16 out ld=N. EPI 2: fused SwiGLU, pair-interleaved B (x1 at even nf, x2 at odd nf) -> hid ld=2752.
template<int EPI>
__global__ __launch_bounds__(256,2) void gemm_dp2(
    const u16* __restrict__ A, const u16* __restrict__ Bw, const float* __restrict__ bias,
    int N, int K, int nbias, u16* __restrict__ outb)
{
  constexpr int AU = 128*32;          // 4096 u16
  constexpr int RU = AU + 256*32;     // 12288 u16 = 24KB
  __shared__ __align__(16) u16 lds[3*RU];
  int t = threadIdx.x;
  int lane = t&63, w = t>>6;
  int wr = w>>1, wc = w&1;            // 2x2 wave grid, wave tile 64x128
  int lr = lane&15, lg = lane>>4;
  // bijective XCD chunk remap (nwg % 8 == 0): each XCD owns contiguous bm-major chunk
  int nbn = gridDim.x;
  int id = blockIdx.y*nbn + blockIdx.x;
  int chunk = (nbn*(int)gridDim.y)>>3;
  int g = (id&7)*chunk + (id>>3);
  int bm = 0;
  while (g >= nbn){ g -= nbn; ++bm; }
  int bn = g;
  int schunk = ((t&3) ^ ((t>>3)&3))*8;
  const u16* pA = A  + (size_t)(bm*128 + (t>>2))*K + schunk;
  const u16* pB = Bw + (size_t)(bn*256 + (t>>2))*K + schunk;
  int rsw  = (lg ^ ((lr>>1)&3))*8;
  int aoff = (wr*64 + lr)*32 + rsw;
  int boff = AU + (wc*128 + lr)*32 + rsw;
  f32x4 acc[4][8] = {};
  int NT = K>>5;

  auto stage = [&](int kt, int rg){
    u16* dst = &lds[rg*RU];
    const u16* sa = pA + (size_t)kt*32;
    const u16* sb = pB + (size_t)kt*32;
    gload16(sa,                  dst + t*8);
    gload16(sa + (size_t)64*K,   dst + 2048 + t*8);
#pragma unroll
    for (int i=0;i<4;i++)
      gload16(sb + (size_t)(i*64)*K, dst + AU + i*2048 + t*8);
  };

  stage(0, 0);
  stage(1, 1);
  asm volatile("s_waitcnt vmcnt(6)" ::: "memory");
  __builtin_amdgcn_s_barrier();
  __builtin_amdgcn_sched_barrier(0);

  int cur = 0, stg = 2;
  for (int kt=0; kt<NT; ++kt){
    const u16* lb = &lds[cur*RU];
    if (kt+2 < NT) stage(kt+2, stg);
    bf16x8 af[4], bfr[8];
#pragma unroll
    for (int mf=0;mf<4;mf++) af[mf] = *(const bf16x8*)&lb[aoff + mf*512];
#pragma unroll
    for (int nf=0;nf<8;nf++) bfr[nf] = *(const bf16x8*)&lb[boff + nf*512];
    __builtin_amdgcn_s_setprio(1);
#pragma unroll
    for (int mf=0;mf<4;mf++)
#pragma unroll
      for (int nf=0;nf<8;nf++)
        acc[mf][nf] = mfma16(af[mf], bfr[nf], acc[mf][nf]);
    __builtin_amdgcn_s_setprio(0);
    if (kt+2 < NT){
      asm volatile("s_waitcnt vmcnt(6)" ::: "memory");
    } else if (kt+1 < NT){
      asm volatile("s_waitcnt vmcnt(0)" ::: "memory");
    }
    if (kt+1 < NT){
      __builtin_amdgcn_s_barrier();
      __builtin_amdgcn_sched_barrier(0);
    }
    cur = (cur==2)?0:cur+1;
    stg = (stg==2)?0:stg+1;
  }
  if constexpr (EPI==0){
#pragma unroll
    for (int nf=0;nf<8;nf++){
      int col = bn*256 + wc*128 + nf*16 + lr;
      float bv = (col < nbias) ? bias[col] : 0.f;
#pragma unroll
      for (int mf=0; mf<4; mf++){
        int row0 = bm*128 + wr*64 + mf*16 + lg*4;
#pragma unroll
        for (int r=0;r<4;r++)
          outb[(size_t)(row0+r)*N + col] = f2b(acc[mf][nf][r] + bv);
      }
    }
  } else {
    // fused SwiGLU, pair-interleaved: even nf = x1, odd nf = x2, same lane, pair col P = p*16+lr.
#pragma unroll
    for (int nf=0;nf<8;nf+=2){
      int p = bn*8 + wc*4 + (nf>>1);
      int P = p*16 + lr;
      bool vP = (P < 2730);
      float b1 = vP ? bias[P] : 0.f;
      float b2 = vP ? bias[2730+P] : 0.f;
#pragma unroll
      for (int mf=0; mf<4; mf++){
        int row0 = bm*128 + wr*64 + mf*16 + lg*4;
#pragma unroll
        for (int r=0;r<4;r++){
          float x1 = acc[mf][nf][r] + b1;
          float x2 = acc[mf][nf+1][r] + b2;
          if (vP) outb[(size_t)(row0+r)*2752 + P] = f2b(silu_f(x1)*x2);
        }
      }
    }
  }
}

// ---------------- qkv repack: rms-norm q,k per head, fragment-major K/V for attention ----------------
__global__ __launch_bounds__(256) void repack_qkv(const u16* __restrict__ qkvO,
    const float* __restrict__ qnw, const float* __restrict__ knw,
    u16* __restrict__ qO, u16* __restrict__ kO, u16* __restrict__ vO)
{
  __shared__ u16 ldsv[64][64];
  int bh = blockIdx.y, b = bh>>4, h = bh&15;
  int n0 = blockIdx.x*64;
  int t = threadIdx.x;
  int nr = t>>2, qd = (t&3)*16;
  const u16* rowp = qkvO + (size_t)(b*1024 + n0 + nr)*3072;
  // Q: rms-norm * qn_w * (1/8)*log2e
  {
    u16x8 a0 = *(const u16x8*)(rowp + h*64 + qd);
    u16x8 a1 = *(const u16x8*)(rowp + h*64 + qd + 8);
    float f[16]; float ss=0;
#pragma unroll
    for (int jj=0;jj<8;jj++){ f[jj]=b2f(a0[jj]); f[8+jj]=b2f(a1[jj]); }
#pragma unroll
    for (int jj=0;jj<16;jj++) ss += f[jj]*f[jj];
    ss += __shfl_xor(ss,1); ss += __shfl_xor(ss,2);
    float rinv = rsqrtf(ss*(1.f/64.f)+1e-6f)*0.125f*1.44269504089f;
    u16x8 o0,o1;
#pragma unroll
    for (int jj=0;jj<8;jj++){ o0[jj]=f2b(f[jj]*rinv*qnw[qd+jj]); o1[jj]=f2b(f[8+jj]*rinv*qnw[qd+8+jj]); }
    u16* dst = qO + ((size_t)bh*1024 + n0 + nr)*64 + qd;
    *(u16x8*)dst = o0; *(u16x8*)(dst+8) = o1;
  }
  // K: rms-norm * kn_w -> fragment-major
  {
    u16x8 a0 = *(const u16x8*)(rowp + 1024 + h*64 + qd);
    u16x8 a1 = *(const u16x8*)(rowp + 1024 + h*64 + qd + 8);
    float f[16]; float ss=0;
#pragma unroll
    for (int jj=0;jj<8;jj++){ f[jj]=b2f(a0[jj]); f[8+jj]=b2f(a1[jj]); }
#pragma unroll
    for (int jj=0;jj<16;jj++) ss += f[jj]*f[jj];
    ss += __shfl_xor(ss,1); ss += __shfl_xor(ss,2);
    float rinv = rsqrtf(ss*(1.f/64.f)+1e-6f);
    u16x8 o0,o1;
#pragma unroll
    for (int jj=0;jj<8;jj++){ o0[jj]=f2b(f[jj]*rinv*knw[qd+jj]); o1[jj]=f2b(f[8+jj]*rinv*knw[qd+8+jj]); }
    int t16 = (n0 + nr)>>4, lrk = nr&15;
    {
      int d0 = qd, c = d0>>5, lg = (d0>>3)&3;
      *(u16x8*)(kO + (size_t)bh*65536 + ((size_t)(t16*2+c)*64 + lg*16 + lrk)*8) = o0;
    }
    {
      int d0 = qd+8, c = d0>>5, lg = (d0>>3)&3;
      *(u16x8*)(kO + (size_t)bh*65536 + ((size_t)(t16*2+c)*64 + lg*16 + lrk)*8) = o1;
    }
  }
  // V: transpose via LDS, then write fragment-major
  {
    u16x8 a0 = *(const u16x8*)(rowp + 2048 + h*64 + qd);
    u16x8 a1 = *(const u16x8*)(rowp + 2048 + h*64 + qd + 8);
#pragma unroll
    for (int jj=0;jj<8;jj++){ ldsv[qd+jj][nr] = a0[jj]; ldsv[qd+8+jj][nr] = a1[jj]; }
  }
  __syncthreads();
  {
    int d = t>>2, ns = (t&3)*16;
    int tt = d>>4, lrv = d&15;
    int m = (n0 + ns)>>5;
    int hf = (ns>>4)&1;
    u16* basep = vO + (size_t)bh*65536 + ((size_t)(m*4+tt)*64 + lrv)*8 + hf*4;
#pragma unroll
    for (int g=0; g<4; ++g){
      u16x4 wv4 = { ldsv[d][ns+g*4], ldsv[d][ns+g*4+1], ldsv[d][ns+g*4+2], ldsv[d][ns+g*4+3] };
      *(u16x4*)(basep + (size_t)g*128) = wv4;
    }
  }
}

// ---------------- flash attention: split-K x2, coalesced fragment loads, defer-max, exp2 ----------------
__global__ __launch_bounds__(512) void attn_fwd(const u16* __restrict__ qO,
    const u16* __restrict__ kO, const u16* __restrict__ vO, u16* __restrict__ o)
{
  __shared__ __align__(16) float obuf[4][64][16];
  __shared__ __align__(16) float mlb[4][2][2][16];
  int bh = blockIdx.y, b = bh>>4, h = bh&15;
  int w = threadIdx.x>>6, lane = threadIdx.x&63;
  int pair = w>>1, half = w&1;
  int lr = lane&15, lg = lane>>4;
  int q0 = blockIdx.x*64 + pair*16;
  const u16* qp = qO + ((size_t)bh*1024 + q0 + lr)*64 + lg*8;
  bf16x8 qf0 = *(const bf16x8*)qp;
  bf16x8 qf1 = *(const bf16x8*)(qp + 32);
  const u16* kb = kO + (size_t)bh*65536 + (size_t)half*32768 + (size_t)lane*8;
  const u16* vb = vO + (size_t)bh*65536 + (size_t)half*32768 + (size_t)lane*8;
  f32x4 oacc[4] = {};
  float mrun = -3.0e38f, lrun = 0.f;
  for (int it=0; it<16; ++it){
    const u16* kp = kb + (size_t)it*4096;
    bf16x8 k00 = *(const bf16x8*)(kp);
    bf16x8 k01 = *(const bf16x8*)(kp + 512);
    bf16x8 k10 = *(const bf16x8*)(kp + 1024);
    bf16x8 k11 = *(const bf16x8*)(kp + 1536);
    f32x4 s0 = {}, s1 = {};
    s0 = mfma16(k00, qf0, s0); s0 = mfma16(k01, qf1, s0);
    s1 = mfma16(k10, qf0, s1); s1 = mfma16(k11, qf1, s1);
    const u16* vp = vb + (size_t)it*2048;
    bf16x8 vv[4];
#pragma unroll
    for (int tt=0;tt<4;tt++) vv[tt] = *(const bf16x8*)(vp + tt*512);
    float pm = fmaxf(fmaxf(fmaxf(s0[0],s0[1]),fmaxf(s0[2],s0[3])),
                     fmaxf(fmaxf(s1[0],s1[1]),fmaxf(s1[2],s1[3])));
    pm = fmaxf(pm, __shfl_xor(pm, 16));
    pm = fmaxf(pm, __shfl_xor(pm, 32));
    if (__any(pm > mrun + 8.f)){
      float mnew = fmaxf(mrun, pm);
      float alpha = fexp2(mrun - mnew);
      mrun = mnew;
      lrun *= alpha;
      float ar[4];
#pragma unroll
      for (int r=0;r<4;r++) ar[r] = __shfl(alpha, lg*4 + r);
#pragma unroll
      for (int tt=0;tt<4;tt++)
#pragma unroll
        for (int r=0;r<4;r++) oacc[tt][r] *= ar[r];
    }
    float p0[4], p1[4]; float ls = 0.f;
#pragma unroll
    for (int r=0;r<4;r++){ p0[r]=fexp2(s0[r]-mrun); p1[r]=fexp2(s1[r]-mrun); ls += p0[r]+p1[r]; }
    ls += __shfl_xor(ls, 16); ls += __shfl_xor(ls, 32);
    lrun += ls;
    bf16x4 pa0, pa1;
#pragma unroll
    for (int r=0;r<4;r++){ pa0[r] = (__bf16)p0[r]; pa1[r] = (__bf16)p1[r]; }
#pragma unroll
    for (int tt=0;tt<4;tt++){
      bf16x4* vh = (bf16x4*)&vv[tt];
      oacc[tt] = mfma16k16(pa0, vh[0], oacc[tt]);
      oacc[tt] = mfma16k16(pa1, vh[1], oacc[tt]);
    }
  }
  if (lg==0){ mlb[pair][half][0][lr] = mrun; mlb[pair][half][1][lr] = lrun; }
  __syncthreads();
  f32x4 m0 = *(const f32x4*)&mlb[pair][0][0][lg*4];
  f32x4 l0 = *(const f32x4*)&mlb[pair][0][1][lg*4];
  f32x4 m1 = *(const f32x4*)&mlb[pair][1][0][lg*4];
  f32x4 l1 = *(const f32x4*)&mlb[pair][1][1][lg*4];
  f32x4 fh;
#pragma unroll
  for (int r=0;r<4;r++){
    float m = fmaxf(m0[r], m1[r]);
    float e0 = fexp2(m0[r]-m), e1 = fexp2(m1[r]-m);
    float li = 1.f/(l0[r]*e0 + l1[r]*e1);
    fh[r] = (half ? e1 : e0)*li;
  }
  if (half==1){
#pragma unroll
    for (int tt=0;tt<4;tt++){
      f32x4 tv;
#pragma unroll
      for (int r=0;r<4;r++) tv[r] = oacc[tt][r]*fh[r];
      *(f32x4*)&obuf[pair][lane][tt*4] = tv;
    }
  }
  __syncthreads();
  if (half==0){
#pragma unroll
    for (int tt=0;tt<4;tt++){
      f32x4 p = *(const f32x4*)&obuf[pair][lane][tt*4];
#pragma unroll
      for (int r=0;r<4;r++){
        int row = (b<<10) + q0 + lg*4 + r;
        int col = h*64 + tt*16 + lr;
        o[(size_t)row*1024 + col] = f2b(oacc[tt][r]*fh[r] + p[r]);
      }
    }
  }
}

extern "C" void kernel_launch(void* const* d_in, const int* in_sizes, int n_in,
                              void* d_out, int out_size, void* d_ws, size_t ws_size,
                              hipStream_t stream)
{
  (void)in_sizes; (void)n_in; (void)out_size; (void)ws_size;
  const float* x    = (const float*)d_in[0];
  const float* c    = (const float*)d_in[1];
  const float* n1w  = (const float*)d_in[2];
  const float* cw   = (const float*)d_in[3];
  const float* cb   = (const float*)d_in[4];
  const float* qkvw = (const float*)d_in[5];
  const float* qkvb = (const float*)d_in[6];
  const float* qnw  = (const float*)d_in[7];
  const float* knw  = (const float*)d_in[8];
  const float* pw   = (const float*)d_in[9];
  const float* pb   = (const float*)d_in[10];
  const float* ew   = (const float*)d_in[11];
  const float* eb   = (const float*)d_in[12];
  const float* n2w  = (const float*)d_in[13];
  const float* w12w = (const float*)d_in[14];
  const float* w12b = (const float*)d_in[15];
  const float* w3w  = (const float*)d_in[16];
  const float* w3b  = (const float*)d_in[17];
  const float* adaw = (const float*)d_in[18];
  const float* adab = (const float*)d_in[19];
  float* out = (float*)d_out;
  char* ws = (char*)d_ws;
  auto U = [&](size_t off){ return (u16*)(ws + off); };
  auto F = [&](size_t off){ return (float*)(ws + off); };

  // weight conversions: merged (wc/qkv/proj/exp/w12-interleaved) + w3
  convert_merged<<<11776, 256, 0, stream>>>(cw, qkvw, pw, ew, w12w, (u16*)ws);
  convert_pad<<<dim3(3,1024), 256, 0, stream>>>(w3w, U(OFF_WW3), 1024, 2730, 2752);

  ada_kernel<<<1536, 256, 0, stream>>>(c, adaw, adab, F(OFF_ADA));

  // attention branch
  rms_mod<<<4096, 256, 0, stream>>>(x, n1w, F(OFF_ADA), 0, U(OFF_H1));
  gemm_dr<0><<<dim3(8,32), 256, 0, stream>>>(U(OFF_H1), U(OFF_WC), cb, 1024, 1024, 1024, U(OFF_HC), nullptr, nullptr, 0, nullptr);
  gemm_dp2<0><<<dim3(12,32), 256, 0, stream>>>(U(OFF_HC), U(OFF_WQKV), qkvb, 3072, 1024, 3072, U(OFF_QKVO));
  repack_qkv<<<dim3(16,64), 256, 0, stream>>>(U(OFF_QKVO), qnw, knw, U(OFF_Q), U(OFF_K), U(OFF_VT));
  attn_fwd<<<dim3(16,64), 512, 0, stream>>>(U(OFF_Q), U(OFF_K), U(OFF_VT), U(OFF_O));
  gemm_dr<0><<<dim3(8,32), 256, 0, stream>>>(U(OFF_O), U(OFF_WPROJ), pb, 1024, 1024, 1024, U(OFF_PR), nullptr, nullptr, 0, nullptr);
  gemm_dr<1><<<dim3(8,32), 256, 0, stream>>>(U(OFF_PR), U(OFF_WEXP), eb, 1024, 1024, 1024, nullptr, x, F(OFF_ADA), 2, F(OFF_X2));

  // FFN branch (w12 + swiglu fused via pair-interleaved weights)
  rms_mod<<<4096, 256, 0, stream>>>(F(OFF_X2), n2w, F(OFF_ADA), 3, U(OFF_H2));
  gemm_dp2<2><<<dim3(22,32), 256, 0, stream>>>(U(OFF_H2), U(OFF_WW12), w12b, 5632, 1024, 5460, U(OFF_HID));
  gemm_dr<1><<<dim3(8,32), 256, 0, stream>>>(U(OFF_HID), U(OFF_WW3), w3b, 1024, 2752, 1024, nullptr, F(OFF_X2), F(OFF_ADA), 5, out);
}